// Round 6
// baseline (727.028 us; speedup 1.0000x reference)
//
#include <hip/hip_runtime.h>
#include <math.h>

typedef unsigned short ushort_t;
typedef __attribute__((ext_vector_type(8))) short short8;
typedef __attribute__((ext_vector_type(4))) float f32x4;
typedef __attribute__((ext_vector_type(4))) unsigned short ushort4v;

constexpr int B_ = 64, S_ = 512, DIM_ = 1024, COV_ = 256, TC_ = 768, KIH_ = 2049;
constexpr int NG_ = 1024, KG_ = 1280;  // gates GEMM: [32768 x KG] @ [KG x NG]

__device__ __forceinline__ float b2f(ushort_t u) {
    union { unsigned int i; float f; } v; v.i = ((unsigned int)u) << 16; return v.f;
}
__device__ __forceinline__ ushort_t f2b(float f) {
    unsigned int x = __float_as_uint(f);
    unsigned int r = x + 0x7fffu + ((x >> 16) & 1u);
    return (ushort_t)(r >> 16);
}
__device__ __forceinline__ float ldv(const float* p, size_t i) { return p[i]; }
__device__ __forceinline__ float ldv(const ushort_t* p, size_t i) { return b2f(p[i]); }

__device__ __forceinline__ float wave_reduce(float a) {
#pragma unroll
    for (int off = 32; off >= 1; off >>= 1) a += __shfl_down(a, off, 64);
    return a;
}

// 4x4 lane<->reg transpose within each 4-lane group (2 butterfly stages).
// In: lane (l&3)=g holds v[r] = T[g][r].  Out: lane (l&3)=q holds v[g] = T[g][q].
__device__ __forceinline__ void xpose4(f32x4& v, int l) {
    float s, r;
    s = (l & 1) ? v[0] : v[1]; r = __shfl_xor(s, 1, 64); if (l & 1) v[0] = r; else v[1] = r;
    s = (l & 1) ? v[2] : v[3]; r = __shfl_xor(s, 1, 64); if (l & 1) v[2] = r; else v[3] = r;
    s = (l & 2) ? v[0] : v[2]; r = __shfl_xor(s, 2, 64); if (l & 2) v[0] = r; else v[2] = r;
    s = (l & 2) ? v[1] : v[3]; r = __shfl_xor(s, 2, 64); if (l & 2) v[1] = r; else v[3] = r;
}

#define GLDS16(src, dst)                                                            \
    __builtin_amdgcn_global_load_lds(                                               \
        (const __attribute__((address_space(1))) void*)(src),                       \
        (__attribute__((address_space(3))) void*)(dst), 16, 0, 0)

// ---- dtype detection: flags[0]=mask_is_bytes, flags[1]=inputs_are_f32 ---------
__global__ void k_detect(const unsigned char* __restrict__ mask,
                         const ushort_t* __restrict__ win,
                         int* __restrict__ flags) {
    __shared__ int red0[256];
    __shared__ int red1[256];
    int tid = threadIdx.x, mb = 0, f32 = 0;
    for (int i = tid; i < 32768; i += 256)
        if ((i & 3) != 0 && mask[i] != 0) mb = 1;
    for (int i = tid; i < 32768; i += 256) {
        ushort_t u = win[2 * i];
        if ((u & 0x7F80u) >= 0x4480u) f32 = 1;
    }
    red0[tid] = mb; red1[tid] = f32; __syncthreads();
    for (int st = 128; st >= 1; st >>= 1) {
        if (tid < st) { red0[tid] |= red0[tid + st]; red1[tid] |= red1[tid + st]; }
        __syncthreads();
    }
    if (tid == 0) { flags[0] = red0[0]; flags[1] = red1[0]; }
}

// ---- generic transpose -> canonical bf16: out[c*R+r] = in[r*ld+off+c] ---------
template <typename IT>
__device__ __forceinline__ void transpose_body(const IT* __restrict__ in,
                                               ushort_t* __restrict__ out,
                                               int R, int C, int ld, int off) {
    int idx = blockIdx.x * 256 + threadIdx.x;
    if (idx >= R * C) return;
    int r = idx / C, c = idx - r * C;
    out[c * R + r] = f2b(ldv(in, (size_t)r * ld + off + c));
}
__global__ void k_transpose(const void* __restrict__ in, ushort_t* __restrict__ out,
                            int R, int C, int ld, int off, const int* __restrict__ flags) {
    if (flags[1]) transpose_body((const float*)in, out, R, C, ld, off);
    else transpose_body((const ushort_t*)in, out, R, C, ld, off);
}

// ---- watt[j] = w_ih[j, 2048] --------------------------------------------------
template <typename IT>
__device__ __forceinline__ void watt_body(const IT* __restrict__ wih, float* __restrict__ watt) {
    int j = threadIdx.x;  // 768 threads
    watt[j] = ldv(wih, (size_t)j * KIH_ + 2048);
}
__global__ void k_watt(const void* __restrict__ wih, float* __restrict__ watt,
                       const int* __restrict__ flags) {
    if (flags[1]) watt_body((const float*)wih, watt);
    else watt_body((const ushort_t*)wih, watt);
}

// ---- bfold[j] = sum_d bcov[d] * w_ih[j, d] ------------------------------------
template <typename IT>
__device__ __forceinline__ void bfold_body(const IT* __restrict__ bcov,
                                           const IT* __restrict__ wih,
                                           float* __restrict__ bfold) {
    int j = blockIdx.x * 4 + (threadIdx.x >> 6);
    int lane = threadIdx.x & 63;
    const IT* wr = wih + (size_t)j * KIH_;
    float a = 0.f;
#pragma unroll
    for (int i = 0; i < 16; ++i) { int k = lane + 64 * i; a += ldv(bcov, k) * ldv(wr, k); }
    a = wave_reduce(a);
    if (lane == 0) bfold[j] = a;
}
__global__ __launch_bounds__(256) void k_bfold(const void* __restrict__ bcov,
                                               const void* __restrict__ wih,
                                               float* __restrict__ bfold,
                                               const int* __restrict__ flags) {
    if (flags[1]) bfold_body((const float*)bcov, (const float*)wih, bfold);
    else bfold_body((const ushort_t*)bcov, (const ushort_t*)wih, bfold);
}

// ---- wfold[c*768+j] = sum_d W_cov[d,c] * w_ih[j,d] ----------------------------
__global__ __launch_bounds__(256) void k_wfold(const ushort_t* __restrict__ wcov_t,
                                               const ushort_t* __restrict__ w_t,
                                               float* __restrict__ wfold) {
    __shared__ float col[DIM_];
    int c = blockIdx.x, tid = threadIdx.x;
    for (int d = tid; d < DIM_; d += 256) col[d] = b2f(wcov_t[c * DIM_ + d]);
    __syncthreads();
    float a0 = 0.f, a1 = 0.f, a2 = 0.f;
    for (int d = 0; d < DIM_; ++d) {
        float x = col[d];
        const ushort_t* wr = w_t + d * TC_;
        a0 += x * b2f(wr[tid]);
        a1 += x * b2f(wr[tid + 256]);
        a2 += x * b2f(wr[tid + 512]);
    }
    wfold[c * TC_ + tid] = a0;
    wfold[c * TC_ + tid + 256] = a1;
    wfold[c * TC_ + tid + 512] = a2;
}

// ---- build Wg_t [NG=1024 rows][KG=1280 cols] bf16, GATE-INTERLEAVED -----------
// new row n = 4*c + g  (g: 0=R,1=Z,2=XN,3=HN) maps to old gate-major row
// j = g*256 + c.  This lets the gemm epilogue see all 4 gates of a channel
// inside one 16-wide MFMA fragment (lanes l^1,l^2,l^3) -> fused GRU activation.
template <typename IT>
__device__ __forceinline__ void buildwg_body(const IT* __restrict__ wih,
                                             const IT* __restrict__ whh,
                                             const float* __restrict__ wfold,
                                             ushort_t* __restrict__ wg) {
    int idx = blockIdx.x * 256 + threadIdx.x;
    if (idx >= NG_ * KG_) return;
    int n = idx / KG_, k = idx - n * KG_;
    int g = n & 3, cq = n >> 2;
    int j = g * COV_ + cq;  // old row index in [0,1024)
    float v;
    if (k < DIM_) {
        v = (j < TC_) ? ldv(wih, (size_t)j * KIH_ + k) : 0.f;
    } else {
        int c = k - DIM_;
        if (j < 512)      v = wfold[c * TC_ + j] + ldv(whh, (size_t)j * COV_ + c);
        else if (j < TC_) v = wfold[c * TC_ + j];
        else              v = ldv(whh, (size_t)(j - 256) * COV_ + c);
    }
    wg[(size_t)n * KG_ + k] = f2b(v);
}
__global__ void k_buildwg(const void* __restrict__ wih, const void* __restrict__ whh,
                          const float* __restrict__ wfold, ushort_t* __restrict__ wg,
                          const int* __restrict__ flags) {
    if (flags[1]) buildwg_body((const float*)wih, (const float*)whh, wfold, wg);
    else buildwg_body((const ushort_t*)wih, (const ushort_t*)whh, wfold, wg);
}

// ---- target = h @ W_in^T (wave per output) ------------------------------------
template <typename IT>
__device__ __forceinline__ void target_body(const IT* __restrict__ h,
                                            const IT* __restrict__ W_in,
                                            float* __restrict__ target) {
    int o = blockIdx.x * 4 + (threadIdx.x >> 6);
    int lane = threadIdx.x & 63;
    int b = o >> 10, d = o & (DIM_ - 1);
    const IT* hr = h + (size_t)b * DIM_;
    const IT* wr = W_in + (size_t)d * DIM_;
    float a = 0.f;
#pragma unroll
    for (int j = 0; j < 16; ++j) { int k = lane + 64 * j; a += ldv(hr, k) * ldv(wr, k); }
    a = wave_reduce(a);
    if (lane == 0) target[o] = a;
}
__global__ __launch_bounds__(256) void k_target_w(const void* __restrict__ h,
                                                  const void* __restrict__ W_in,
                                                  float* __restrict__ target,
                                                  const int* __restrict__ flags) {
    if (flags[1]) target_body((const float*)h, (const float*)W_in, target);
    else target_body((const ushort_t*)h, (const ushort_t*)W_in, target);
}

// ---- mvec[b,c] = sum_d target[b,d]*W_cov[d,c];  bct[b] = sum_d target*b_cov ---
// v2: grid (B, 4) -> 256 blocks (was 64; 3/4 of CUs idle).  Block (b,q) does
// channels q*64..q*64+63 with 256 threads = 64 ch x 4 d-groups (serial 256).
template <typename IT>
__device__ __forceinline__ void mvec_body(const float* __restrict__ target,
                                          const IT* __restrict__ W_cov,
                                          const IT* __restrict__ bcov,
                                          float* __restrict__ mvec,
                                          float* __restrict__ bct) {
    __shared__ float tg[DIM_];
    __shared__ float red[256];
    int b = blockIdx.x, q = blockIdx.y, tid = threadIdx.x;
    float pb = 0.f;
    for (int k = tid; k < DIM_; k += 256) {
        float t = target[b * DIM_ + k];
        tg[k] = t; pb += t * ldv(bcov, k);
    }
    red[tid] = pb; __syncthreads();
    for (int st = 128; st >= 1; st >>= 1) {
        if (tid < st) red[tid] += red[tid + st];
        __syncthreads();
    }
    if (q == 0 && tid == 0) bct[b] = red[0];
    __syncthreads();  // red[0] read complete before red is reused below
    int cg = tid & 63, dg = tid >> 6;
    int c = q * 64 + cg;
    float acc = 0.f;
    int d0 = dg * 256;
    for (int d = d0; d < d0 + 256; ++d) acc += tg[d] * ldv(W_cov, (size_t)d * COV_ + c);
    red[dg * 64 + cg] = acc;
    __syncthreads();
    if (dg == 0)
        mvec[b * COV_ + c] = red[cg] + red[64 + cg] + red[128 + cg] + red[192 + cg];
}
__global__ __launch_bounds__(256) void k_mvec(const float* __restrict__ target,
                                              const void* __restrict__ W_cov,
                                              const void* __restrict__ bcov,
                                              float* __restrict__ mvec,
                                              float* __restrict__ bct,
                                              const int* __restrict__ flags) {
    if (flags[1]) mvec_body(target, (const float*)W_cov, (const float*)bcov, mvec, bct);
    else mvec_body(target, (const ushort_t*)W_cov, (const ushort_t*)bcov, mvec, bct);
}

// ---- raw scores + fused f32->bf16 conversion ----------------------------------
// f32 path: float4-vectorized dot; also writes the bf16 copies of ctx/cov
// (replaces the separate k_cvt pass: saves a full 168 MB f32 re-read).
template <typename IT>
__device__ __forceinline__ void scoreraw_body(const IT* __restrict__ context,
                                              const IT* __restrict__ cov,
                                              const float* __restrict__ target,
                                              const float* __restrict__ mvec,
                                              const float* __restrict__ bct,
                                              float* __restrict__ scf,
                                              ushort_t* __restrict__ ctx_bf,
                                              ushort_t* __restrict__ cov_bf) {
    __shared__ float tg[DIM_];
    __shared__ float ms[COV_];
    int b = blockIdx.x, tid = threadIdx.x;
    for (int k = tid; k < DIM_; k += 256) tg[k] = target[b * DIM_ + k];
    if (tid < COV_) ms[tid] = mvec[b * COV_ + tid];
    float bc = bct[b];
    __syncthreads();
    int wave = tid >> 6, lane = tid & 63;
    int s0 = blockIdx.y * 64 + wave * 16;
    for (int i = 0; i < 16; ++i) {
        int s = s0 + i;
        size_t row = (size_t)(b * S_ + s);
        const IT* cr = context + row * DIM_;
        const IT* vr = cov + row * COV_;
        float a = 0.f;
        if constexpr (sizeof(IT) == 4) {
#pragma unroll
            for (int j = 0; j < 4; ++j) {
                int d = lane * 4 + 256 * j;
                float4 x = *(const float4*)((const float*)cr + d);
                a += x.x * tg[d] + x.y * tg[d + 1] + x.z * tg[d + 2] + x.w * tg[d + 3];
                if (ctx_bf) {
                    ushort4v u;
                    u[0] = f2b(x.x); u[1] = f2b(x.y); u[2] = f2b(x.z); u[3] = f2b(x.w);
                    *(ushort4v*)(ctx_bf + row * DIM_ + d) = u;
                }
            }
            {
                int cc = lane * 4;
                float4 x = *(const float4*)((const float*)vr + cc);
                a += x.x * ms[cc] + x.y * ms[cc + 1] + x.z * ms[cc + 2] + x.w * ms[cc + 3];
                if (cov_bf) {
                    ushort4v u;
                    u[0] = f2b(x.x); u[1] = f2b(x.y); u[2] = f2b(x.z); u[3] = f2b(x.w);
                    *(ushort4v*)(cov_bf + row * COV_ + cc) = u;
                }
            }
        } else {
#pragma unroll
            for (int j = 0; j < 16; ++j) { int d = lane + 64 * j; a += ldv(cr, d) * tg[d]; }
#pragma unroll
            for (int j = 0; j < 4; ++j) { int c = lane + 64 * j; a += ldv(vr, c) * ms[c]; }
        }
        a = wave_reduce(a);
        if (lane == 0) scf[row] = a + bc;
    }
}
__global__ __launch_bounds__(256) void k_scoreraw(const void* __restrict__ context,
                                                  const void* __restrict__ cov,
                                                  const float* __restrict__ target,
                                                  const float* __restrict__ mvec,
                                                  const float* __restrict__ bct,
                                                  float* __restrict__ scf,
                                                  ushort_t* __restrict__ ctx_bf,
                                                  ushort_t* __restrict__ cov_bf,
                                                  const int* __restrict__ flags) {
    if (flags[1]) scoreraw_body((const float*)context, (const float*)cov, target, mvec, bct,
                                scf, ctx_bf, cov_bf);
    else scoreraw_body((const ushort_t*)context, (const ushort_t*)cov, target, mvec, bct,
                       scf, ctx_bf, cov_bf);
}

// ---- masked softmax over scf --------------------------------------------------
__global__ __launch_bounds__(256) void k_softmax(const float* __restrict__ scf,
                                                 const void* __restrict__ maskp,
                                                 const int* __restrict__ flags,
                                                 float* __restrict__ attnf,
                                                 float* __restrict__ attn_out) {
    __shared__ float red[256];
    int b = blockIdx.x, tid = threadIdx.x;
    int mb = flags[0];
    int i0 = b * S_ + tid, i1 = i0 + 256;
    int m0 = mb ? (int)((const unsigned char*)maskp)[i0] : ((const int*)maskp)[i0];
    int m1 = mb ? (int)((const unsigned char*)maskp)[i1] : ((const int*)maskp)[i1];
    float s0 = m0 ? -INFINITY : scf[i0];
    float s1 = m1 ? -INFINITY : scf[i1];
    red[tid] = fmaxf(s0, s1); __syncthreads();
    for (int st = 128; st >= 1; st >>= 1) {
        if (tid < st) red[tid] = fmaxf(red[tid], red[tid + st]);
        __syncthreads();
    }
    float mx = red[0]; __syncthreads();
    float e0 = expf(s0 - mx), e1 = expf(s1 - mx);
    red[tid] = e0 + e1; __syncthreads();
    for (int st = 128; st >= 1; st >>= 1) {
        if (tid < st) red[tid] += red[tid + st];
        __syncthreads();
    }
    float inv = 1.0f / red[0];
    float a0 = e0 * inv, a1 = e1 * inv;
    attnf[i0] = a0; attnf[i1] = a1;
    attn_out[i0] = a0; attn_out[i1] = a1;
}

// ---- wc partials (bf16 inputs): grid (B, 8); each block sums 64 s-rows --------
__global__ __launch_bounds__(256) void k_wcpart2(const ushort_t* __restrict__ ctx_bf,
                                                 const ushort_t* __restrict__ cov_bf,
                                                 const void* __restrict__ ctx_in,
                                                 const void* __restrict__ cov_in,
                                                 const float* __restrict__ attnf,
                                                 float* __restrict__ wc8,
                                                 float* __restrict__ ac8,
                                                 const int* __restrict__ flags) {
    const ushort_t* C = flags[1] ? ctx_bf : (const ushort_t*)ctx_in;
    const ushort_t* V = flags[1] ? cov_bf : (const ushort_t*)cov_in;
    __shared__ float at[64];
    int b = blockIdx.x, ch = blockIdx.y, tid = threadIdx.x;
    int s0 = ch * 64;
    if (tid < 64) at[tid] = attnf[b * S_ + s0 + tid];
    __syncthreads();
    float acv = 0.f;
    for (int s = 0; s < 64; ++s)
        acv += at[s] * b2f(V[((size_t)(b * S_ + s0 + s)) * COV_ + tid]);
    ac8[((size_t)ch * B_ + b) * COV_ + tid] = acv;
    float acc[4] = {0.f, 0.f, 0.f, 0.f};
    for (int s = 0; s < 64; ++s) {
        float w = at[s];
        const ushort_t* cr = C + ((size_t)(b * S_ + s0 + s)) * DIM_;
        acc[0] += w * b2f(cr[tid]);
        acc[1] += w * b2f(cr[tid + 256]);
        acc[2] += w * b2f(cr[tid + 512]);
        acc[3] += w * b2f(cr[tid + 768]);
    }
    size_t base = ((size_t)ch * B_ + b) * DIM_;
    for (int m = 0; m < 4; ++m) wc8[base + tid + 256 * m] = acc[m];
}

// ---- wc final: reduce partials + ac@W_cov^T + b_cov ---------------------------
template <typename IT>
__device__ __forceinline__ void wcfin_body(const float* __restrict__ wc8,
                                           const float* __restrict__ ac8,
                                           const ushort_t* __restrict__ wcov_t,
                                           const IT* __restrict__ bcov,
                                           float* __restrict__ wc) {
    __shared__ float ac[COV_];
    int b = blockIdx.x, tid = threadIdx.x;
    float a = 0.f;
    for (int ch = 0; ch < 8; ++ch) a += ac8[((size_t)ch * B_ + b) * COV_ + tid];
    ac[tid] = a;
    __syncthreads();
    float acc[4] = {0.f, 0.f, 0.f, 0.f};
    for (int ch = 0; ch < 8; ++ch) {
        size_t base = ((size_t)ch * B_ + b) * DIM_;
        for (int m = 0; m < 4; ++m) acc[m] += wc8[base + tid + 256 * m];
    }
    for (int c = 0; c < COV_; ++c) {
        float av = ac[c];
        const ushort_t* wr = wcov_t + c * DIM_;
        acc[0] += av * b2f(wr[tid]);
        acc[1] += av * b2f(wr[tid + 256]);
        acc[2] += av * b2f(wr[tid + 512]);
        acc[3] += av * b2f(wr[tid + 768]);
    }
    for (int m = 0; m < 4; ++m) {
        int d = tid + 256 * m;
        wc[b * DIM_ + d] = acc[m] + ldv(bcov, d);
    }
}
__global__ __launch_bounds__(256) void k_wcfin(const float* __restrict__ wc8,
                                               const float* __restrict__ ac8,
                                               const ushort_t* __restrict__ wcov_t,
                                               const void* __restrict__ bcov,
                                               float* __restrict__ wc,
                                               const int* __restrict__ flags) {
    if (flags[1]) wcfin_body(wc8, ac8, wcov_t, (const float*)bcov, wc);
    else wcfin_body(wc8, ac8, wcov_t, (const ushort_t*)bcov, wc);
}

// ---- h_tilde = tanh([wc, h] @ W_out^T) (wave per output) ----------------------
template <typename IT>
__device__ __forceinline__ void htilde_body(const float* __restrict__ wc,
                                            const IT* __restrict__ h,
                                            const IT* __restrict__ W_out,
                                            float* __restrict__ out_ht) {
    int o = blockIdx.x * 4 + (threadIdx.x >> 6);
    int lane = threadIdx.x & 63;
    int b = o >> 10, d = o & (DIM_ - 1);
    const float* wcr = wc + b * DIM_;
    const IT* hr = h + (size_t)b * DIM_;
    const IT* wr = W_out + (size_t)d * 2 * DIM_;
    float a = 0.f;
#pragma unroll
    for (int j = 0; j < 16; ++j) { int k = lane + 64 * j; a += wcr[k] * ldv(wr, k); }
#pragma unroll
    for (int j = 0; j < 16; ++j) { int k = lane + 64 * j; a += ldv(hr, k) * ldv(wr, DIM_ + k); }
    a = wave_reduce(a);
    if (lane == 0) out_ht[o] = tanhf(a);
}
__global__ __launch_bounds__(256) void k_htilde_w(const float* __restrict__ wc,
                                                  const void* __restrict__ h,
                                                  const void* __restrict__ W_out,
                                                  float* __restrict__ out_ht,
                                                  const int* __restrict__ flags) {
    if (flags[1]) htilde_body(wc, (const float*)h, (const float*)W_out, out_ht);
    else htilde_body(wc, (const ushort_t*)h, (const ushort_t*)W_out, out_ht);
}

// ---- gxall[b,j] = b_ih[j] + bfold[j] + sum_k h[b,k]*w_ih[j,1024+k] ------------
template <typename IT>
__device__ __forceinline__ void gxh_body(const IT* __restrict__ h,
                                         const IT* __restrict__ w_ih,
                                         const IT* __restrict__ b_ih,
                                         const float* __restrict__ bfold,
                                         float* __restrict__ gxall) {
    int o = blockIdx.x * 4 + (threadIdx.x >> 6);
    int lane = threadIdx.x & 63;
    int b = o / TC_, j = o - b * TC_;
    const IT* hr = h + (size_t)b * DIM_;
    const IT* wr = w_ih + (size_t)j * KIH_ + DIM_;
    float a = 0.f;
#pragma unroll
    for (int i = 0; i < 16; ++i) { int k = lane + 64 * i; a += ldv(hr, k) * ldv(wr, k); }
    a = wave_reduce(a);
    if (lane == 0) gxall[o] = a + ldv(b_ih, j) + bfold[j];
}
__global__ __launch_bounds__(256) void k_gxh_w(const void* __restrict__ h,
                                               const void* __restrict__ w_ih,
                                               const void* __restrict__ b_ih,
                                               const float* __restrict__ bfold,
                                               float* __restrict__ gxall,
                                               const int* __restrict__ flags) {
    if (flags[1]) gxh_body((const float*)h, (const float*)w_ih, (const float*)b_ih, bfold, gxall);
    else gxh_body((const ushort_t*)h, (const ushort_t*)w_ih, (const ushort_t*)b_ih, bfold, gxall);
}

// ---- MFMA gates GEMM v6: BK=64 (2x work per barrier) + unroll-2 dbuf ----------
// Round-5 postmortem: kernel is barrier-drain latency-bound (MfmaUtil 24%,
// VALUBusy 29%, HBM 11% -- all idle). BK 32->64 halves the number of vmcnt(0)
// drains (40->20) and doubles the compute cover per drain.  LDS 64 KB
// (2 blocks/CU = current effective residency, no loss).  Swizzle: 8 sections
// of 8 elems per 128B row, sec_phys = sec_log ^ (row&7); lanes spread evenly
// over the 8 bank-groups -> no extra conflicts (same property as BK=32 v3).
__global__ __launch_bounds__(256) void k_gemm6(const ushort_t* __restrict__ ctx_bf,
                                               const ushort_t* __restrict__ cov_bf,
                                               const void* __restrict__ ctx_in,
                                               const void* __restrict__ cov_in,
                                               const ushort_t* __restrict__ wg,
                                               const float* __restrict__ attnf,
                                               const float* __restrict__ gxall,
                                               const float* __restrict__ watt,
                                               const void* __restrict__ bhh,
                                               float* __restrict__ out_cov,
                                               const int* __restrict__ flags) {
    const int f32in = flags[1];
    const ushort_t* Xc = f32in ? ctx_bf : (const ushort_t*)ctx_in;
    const ushort_t* Xv = f32in ? cov_bf : (const ushort_t*)cov_in;
    // 64 KB: [A0|B0|A1|B1] each 128x64 bf16 = 16 KB.  Epilogue reuses the
    // first 33.8 KB as two padded [128][33] f32 arrays (n, z).
    __shared__ __align__(16) unsigned char smem[65536];
    ushort_t* A0 = (ushort_t*)smem;
    ushort_t* B0 = A0 + 8192;
    ushort_t* A1 = B0 + 8192;
    ushort_t* B1 = A1 + 8192;
    float* smN = (float*)smem;            // [128][33]
    float* smZ = smN + 128 * 33;          // [128][33]

    int tid = threadIdx.x;
    // XCD-aware bijective swizzle (nrb = 256 divisible by 8)
    int p = blockIdx.x;
    int xcd = p & 7, t = p >> 3;
    int nb = t & 7, rb = xcd + 8 * (t >> 3);
    int n0 = nb * 128;
    int grow0 = rb * 128;
    int wave = tid >> 6, lane = tid & 63;
    int wm = wave >> 1, wn = wave & 1;
    int half = lane >> 4, r16 = lane & 15;

    // staging: 1024 16B-chunks/tile; thread handles c = wave*256 + j*64 + lane.
    // row = c>>3, sec_phys = c&7, sec_log = sec_phys ^ (row&7).
    // Global src is per-lane (pre-swizzled); LDS dst is wave-uniform + lane*16B.
    const ushort_t* gAc[4]; const ushort_t* gAv[4]; const ushort_t* gB[4];
    int ldsOff[4];
#pragma unroll
    for (int j = 0; j < 4; ++j) {
        int c = wave * 256 + j * 64 + lane;
        int row = c >> 3, sl = (c & 7) ^ ((c >> 3) & 7);
        gAc[j] = Xc + (size_t)(grow0 + row) * DIM_ + sl * 8;
        gAv[j] = Xv + (size_t)(grow0 + row) * COV_ + sl * 8;
        gB[j]  = wg + (size_t)(n0 + row) * KG_ + sl * 8;
        ldsOff[j] = (wave * 256 + j * 64) * 8;
    }

    // ds_read element offsets: k-half kh (k = kh*32 + half*8 ..+7),
    // sec_log = kh*4 + half, sec_phys = sec_log ^ (row&7).
    int offA[2][4], offB[2][4];
#pragma unroll
    for (int kh = 0; kh < 2; ++kh)
#pragma unroll
        for (int u = 0; u < 4; ++u) {
            int rA = wm * 64 + u * 16 + r16;
            offA[kh][u] = rA * 64 + ((kh * 4 + half) ^ (rA & 7)) * 8;
            int rB = wn * 64 + u * 16 + r16;
            offB[kh][u] = rB * 64 + ((kh * 4 + half) ^ (rB & 7)) * 8;
        }

    f32x4 acc[4][4];
#pragma unroll
    for (int i = 0; i < 4; ++i)
#pragma unroll
        for (int j = 0; j < 4; ++j) acc[i][j] = (f32x4){0.f, 0.f, 0.f, 0.f};

    auto stage = [&](int kt, ushort_t* Ad, ushort_t* Bd) {
        int k0 = kt * 64;
        if (k0 < DIM_) {
#pragma unroll
            for (int j = 0; j < 4; ++j) GLDS16(gAc[j] + k0, Ad + ldsOff[j]);
        } else {
            int kk = k0 - DIM_;
#pragma unroll
            for (int j = 0; j < 4; ++j) GLDS16(gAv[j] + kk, Ad + ldsOff[j]);
        }
#pragma unroll
        for (int j = 0; j < 4; ++j) GLDS16(gB[j] + k0, Bd + ldsOff[j]);
    };
    auto compute = [&](const ushort_t* Ac, const ushort_t* Bc) {
#pragma unroll
        for (int kh = 0; kh < 2; ++kh) {
            short8 a[4], b[4];
#pragma unroll
            for (int u = 0; u < 4; ++u) a[u] = *(const short8*)&Ac[offA[kh][u]];
#pragma unroll
            for (int u = 0; u < 4; ++u) b[u] = *(const short8*)&Bc[offB[kh][u]];
#pragma unroll
            for (int i = 0; i < 4; ++i)
#pragma unroll
                for (int j = 0; j < 4; ++j)
                    acc[i][j] = __builtin_amdgcn_mfma_f32_16x16x32_bf16(a[i], b[j], acc[i][j], 0, 0, 0);
        }
    };

    constexpr int NT = KG_ / 64;  // 20 (even)
    stage(0, A0, B0);
    __syncthreads();
#pragma unroll 1
    for (int kt = 0; kt < NT; kt += 2) {
        stage(kt + 1, A1, B1);      // prefetch odd tile while computing even
        compute(A0, B0);
        __syncthreads();            // drains vmcnt(0): A1/B1 resident
        if (kt + 2 < NT) stage(kt + 2, A0, B0);
        compute(A1, B1);
        __syncthreads();
    }

    // ---- fused GRU epilogue ----
    // MFMA C/D: col = lane&15, row = (lane>>4)*4 + reg.  col = 4c+g with
    // g = lane&3.  After xpose4, lane (l&3)=q holds v[g] = gate g, row-offset q.
    int l = lane;
    int bb = grow0 >> 9;  // 128-row tile never crosses a batch (512 rows/batch)
    const float* gx = gxall + bb * TC_;
    int rloc[4]; float atv[4];
#pragma unroll
    for (int i = 0; i < 4; ++i) {
        rloc[i] = wm * 64 + 16 * i + ((l >> 4) << 2) + (l & 3);
        atv[i] = attnf[grow0 + rloc[i]];
    }
#pragma unroll
    for (int j = 0; j < 4; ++j) {
        int cl = wn * 16 + 4 * j + ((l >> 2) & 3);   // channel local 0..31
        int c = (n0 >> 2) + cl;                       // global channel
        float gxR = gx[c], gxZ = gx[COV_ + c], gxN = gx[2 * COV_ + c];
        float waR = watt[c], waZ = watt[COV_ + c], waN = watt[2 * COV_ + c];
        float bhR, bhZ, bhN;
        if (f32in) {
            const float* bp = (const float*)bhh;
            bhR = bp[c]; bhZ = bp[COV_ + c]; bhN = bp[2 * COV_ + c];
        } else {
            const ushort_t* bp = (const ushort_t*)bhh;
            bhR = b2f(bp[c]); bhZ = b2f(bp[COV_ + c]); bhN = b2f(bp[2 * COV_ + c]);
        }
#pragma unroll
        for (int i = 0; i < 4; ++i) {
            f32x4 v = acc[i][j];
            xpose4(v, l);
            float at = atv[i];
            float aR  = v[0] + gxR + at * waR + bhR;
            float aZ  = v[1] + gxZ + at * waZ + bhZ;
            float aXN = v[2] + gxN + at * waN;
            float aHN = v[3] + bhN;
            float r = 1.f / (1.f + expf(-aR));
            float z = 1.f / (1.f + expf(-aZ));
            float nn = tanhf(aXN + r * aHN);
            smN[rloc[i] * 33 + cl] = nn;
            smZ[rloc[i] * 33 + cl] = z;
        }
    }
    __syncthreads();
    // coalesced blend + write: 8 lanes cover one row's full 128B line
    int cbase = nb * 32;
    for (int u = tid; u < 128 * 8; u += 256) {
        int rl = u >> 3, c4 = (u & 7) * 4;
        float n0v = smN[rl * 33 + c4 + 0], n1v = smN[rl * 33 + c4 + 1];
        float n2v = smN[rl * 33 + c4 + 2], n3v = smN[rl * 33 + c4 + 3];
        float z0 = smZ[rl * 33 + c4 + 0], z1 = smZ[rl * 33 + c4 + 1];
        float z2 = smZ[rl * 33 + c4 + 2], z3 = smZ[rl * 33 + c4 + 3];
        size_t base = (size_t)(grow0 + rl) * COV_ + cbase + c4;
        float h0v, h1v, h2v, h3v;
        if (f32in) {
            float4 hv = *(const float4*)((const float*)cov_in + base);
            h0v = hv.x; h1v = hv.y; h2v = hv.z; h3v = hv.w;
        } else {
            ushort4v hv = *(const ushort4v*)((const ushort_t*)cov_in + base);
            h0v = b2f(hv[0]); h1v = b2f(hv[1]); h2v = b2f(hv[2]); h3v = b2f(hv[3]);
        }
        float4 o;
        o.x = (1.f - z0) * n0v + z0 * h0v;
        o.y = (1.f - z1) * n1v + z1 * h1v;
        o.z = (1.f - z2) * n2v + z2 * h2v;
        o.w = (1.f - z3) * n3v + z3 * h3v;
        *(float4*)(out_cov + base) = o;
    }
}

// ---- legacy GRU (fallback when ws too small) ----------------------------------
template <typename IT>
__device__ __forceinline__ void gru_body(const IT* __restrict__ context,
                                         const IT* __restrict__ cov,
                                         const float* __restrict__ attnf,
                                         const float* __restrict__ gxall,
                                         const float* __restrict__ watt,
                                         const ushort_t* __restrict__ w_t,
                                         const float* __restrict__ wfold,
                                         const ushort_t* __restrict__ whh_t,
                                         const IT* __restrict__ bhh,
                                         float* __restrict__ out_cov) {
    __shared__ float xc[8][DIM_];
    __shared__ float h0s[8][COV_];
    __shared__ float atn[8];
    int base = blockIdx.x * 8, tid = threadIdx.x;
    int b = base / S_;
    for (int i = tid; i < 8 * DIM_; i += 256)
        ((float*)xc)[i] = ldv(context, (size_t)base * DIM_ + i);
    for (int i = tid; i < 8 * COV_; i += 256)
        ((float*)h0s)[i] = ldv(cov, (size_t)base * COV_ + i);
    if (tid < 8) atn[tid] = attnf[base + tid];
    __syncthreads();
    int c = tid;
    float gxR = gxall[b * TC_ + c], gxZ = gxall[b * TC_ + 256 + c], gxN = gxall[b * TC_ + 512 + c];
    float bhR = ldv(bhh, c), bhZ = ldv(bhh, 256 + c), bhN = ldv(bhh, 512 + c);
    float waR = watt[c], waZ = watt[256 + c], waN = watt[512 + c];
    float aR[8], aZ[8], aXN[8], aHN[8];
#pragma unroll
    for (int g = 0; g < 8; ++g) {
        float a = atn[g];
        aR[g] = gxR + bhR + a * waR;
        aZ[g] = gxZ + bhZ + a * waZ;
        aXN[g] = gxN + a * waN;
        aHN[g] = bhN;
    }
    for (int k = 0; k < DIM_; ++k) {
        const ushort_t* row = w_t + k * TC_;
        float wr = b2f(row[c]), wz = b2f(row[256 + c]), wn = b2f(row[512 + c]);
#pragma unroll
        for (int g = 0; g < 8; ++g) {
            float x = xc[g][k];
            aR[g] += x * wr; aZ[g] += x * wz; aXN[g] += x * wn;
        }
    }
    for (int k = 0; k < COV_; ++k) {
        const float* row = wfold + k * TC_;
        float wr = row[c], wz = row[256 + c], wn = row[512 + c];
#pragma unroll
        for (int g = 0; g < 8; ++g) {
            float x = h0s[g][k];
            aR[g] += x * wr; aZ[g] += x * wz; aXN[g] += x * wn;
        }
    }
    for (int k = 0; k < COV_; ++k) {
        const ushort_t* row = whh_t + k * TC_;
        float wr = b2f(row[c]), wz = b2f(row[256 + c]), wn = b2f(row[512 + c]);
#pragma unroll
        for (int g = 0; g < 8; ++g) {
            float hh = h0s[g][k];
            aR[g] += hh * wr; aZ[g] += hh * wz; aHN[g] += hh * wn;
        }
    }
#pragma unroll
    for (int g = 0; g < 8; ++g) {
        float r = 1.f / (1.f + expf(-aR[g]));
        float z = 1.f / (1.f + expf(-aZ[g]));
        float n = tanhf(aXN[g] + r * aHN[g]);
        float h0c = h0s[g][c];
        out_cov[(size_t)(base + g) * COV_ + c] = (1.f - z) * n + z * h0c;
    }
}
__global__ __launch_bounds__(256) void k_gru_f(const void* __restrict__ context,
                                               const void* __restrict__ cov,
                                               const float* __restrict__ attnf,
                                               const float* __restrict__ gxall,
                                               const float* __restrict__ watt,
                                               const ushort_t* __restrict__ w_t,
                                               const float* __restrict__ wfold,
                                               const ushort_t* __restrict__ whh_t,
                                               const void* __restrict__ bhh,
                                               float* __restrict__ out_cov,
                                               const int* __restrict__ flags) {
    if (flags[1]) gru_body((const float*)context, (const float*)cov, attnf, gxall, watt,
                           w_t, wfold, whh_t, (const float*)bhh, out_cov);
    else gru_body((const ushort_t*)context, (const ushort_t*)cov, attnf, gxall, watt,
                  w_t, wfold, whh_t, (const ushort_t*)bhh, out_cov);
}

extern "C" void kernel_launch(void* const* d_in, const int* in_sizes, int n_in,
                              void* d_out, int out_size, void* d_ws, size_t ws_size,
                              hipStream_t stream) {
    const void* h       = d_in[0];
    const void* context = d_in[1];
    const void* cov     = d_in[2];
    const void* W_in    = d_in[3];
    const void* W_out   = d_in[4];
    const void* W_cov   = d_in[5];
    const void* b_cov   = d_in[6];
    const void* w_ih    = d_in[7];
    const void* w_hh    = d_in[8];
    const void* b_ih    = d_in[9];
    const void* b_hh    = d_in[10];
    const void* maskp   = d_in[11];

    float* out = (float*)d_out;
    float* out_ht   = out;
    float* out_attn = out + B_ * DIM_;
    float* out_cov  = out + B_ * DIM_ + B_ * S_;

    char* ws = (char*)d_ws;
    size_t o = 0;
    float* target = (float*)(ws + o); o += (size_t)B_ * DIM_ * 4;
    float* attnf  = (float*)(ws + o); o += (size_t)B_ * S_ * 4;
    float* wc     = (float*)(ws + o); o += (size_t)B_ * DIM_ * 4;
    float* gxall  = (float*)(ws + o); o += (size_t)B_ * TC_ * 4;
    float* watt   = (float*)(ws + o); o += 4096;
    float* mvec   = (float*)(ws + o); o += (size_t)B_ * COV_ * 4;
    float* bct    = (float*)(ws + o); o += 4096;
    float* bfold  = (float*)(ws + o); o += 4096;
    float* wfold  = (float*)(ws + o); o += (size_t)COV_ * TC_ * 4;
    ushort_t* w_t    = (ushort_t*)(ws + o); o += (size_t)DIM_ * TC_ * 2;
    ushort_t* whh_t  = (ushort_t*)(ws + o); o += (size_t)COV_ * TC_ * 2;
    ushort_t* wcov_t = (ushort_t*)(ws + o); o += (size_t)COV_ * DIM_ * 2;
    int* flags = (int*)(ws + o); o += 256;
    float* scf   = (float*)(ws + o); o += (size_t)B_ * S_ * 4;
    float* wc8   = (float*)(ws + o); o += (size_t)8 * B_ * DIM_ * 4;
    float* ac8   = (float*)(ws + o); o += (size_t)8 * B_ * COV_ * 4;
    ushort_t* wg = (ushort_t*)(ws + o); o += (size_t)NG_ * KG_ * 2;
    ushort_t* ctx_bf = (ushort_t*)(ws + o); o += (size_t)B_ * S_ * DIM_ * 2;  // 67 MB
    ushort_t* cov_bf = (ushort_t*)(ws + o); o += (size_t)B_ * S_ * COV_ * 2;  // 17 MB
    size_t fixed = o;

    const size_t TOTAL_ROWS = (size_t)B_ * S_;  // 32768
    const bool fused = ws_size >= fixed;        // no G buffer needed anymore

    // dtype detection + weight prep
    k_detect<<<1, 256, 0, stream>>>((const unsigned char*)maskp, (const ushort_t*)W_in, flags);
    k_transpose<<<(TC_ * DIM_) / 256, 256, 0, stream>>>(w_ih, w_t, TC_, DIM_, KIH_, 0, flags);
    k_transpose<<<(DIM_ * COV_) / 256, 256, 0, stream>>>(W_cov, wcov_t, DIM_, COV_, COV_, 0, flags);
    if (!fused)
        k_transpose<<<(TC_ * COV_) / 256, 256, 0, stream>>>(w_hh, whh_t, TC_, COV_, COV_, 0, flags);
    k_watt<<<1, TC_, 0, stream>>>(w_ih, watt, flags);
    k_bfold<<<TC_ / 4, 256, 0, stream>>>(b_cov, w_ih, bfold, flags);
    k_wfold<<<COV_, 256, 0, stream>>>(wcov_t, w_t, wfold);
    if (fused)
        k_buildwg<<<(NG_ * KG_ + 255) / 256, 256, 0, stream>>>(w_ih, w_hh, wfold, wg, flags);

    // attention path (scoreraw also emits the bf16 copies of ctx/cov)
    k_target_w<<<(B_ * DIM_) / 4, 256, 0, stream>>>(h, W_in, target, flags);
    k_mvec<<<dim3(B_, 4), 256, 0, stream>>>(target, W_cov, b_cov, mvec, bct, flags);
    k_scoreraw<<<dim3(B_, 8), 256, 0, stream>>>(context, cov, target, mvec, bct, scf,
                                                fused ? ctx_bf : nullptr,
                                                fused ? cov_bf : nullptr, flags);
    k_softmax<<<B_, 256, 0, stream>>>(scf, maskp, flags, attnf, out_attn);
    if (fused)
        k_wcpart2<<<dim3(B_, 8), 256, 0, stream>>>(ctx_bf, cov_bf, context, cov, attnf,
                                                   wc8, ac8, flags);
    else
        k_wcpart2<<<dim3(B_, 8), 256, 0, stream>>>((const ushort_t*)context, (const ushort_t*)cov,
                                                   context, cov, attnf, wc8, ac8, flags);
    k_wcfin<<<B_, 256, 0, stream>>>(wc8, ac8, wcov_t, b_cov, wc, flags);
    k_htilde_w<<<(B_ * DIM_) / 4, 256, 0, stream>>>(wc, h, W_out, out_ht, flags);

    // GRU coverage path (single fused GEMM+activation)
    k_gxh_w<<<(B_ * TC_) / 4, 256, 0, stream>>>(h, w_ih, b_ih, bfold, gxall, flags);
    if (fused) {
        int nblk = (int)(TOTAL_ROWS / 128) * (NG_ / 128);  // 2048
        k_gemm6<<<nblk, 256, 0, stream>>>(ctx_bf, cov_bf, context, cov, wg, attnf,
                                          gxall, watt, b_hh, out_cov, flags);
    } else {
        k_gru_f<<<(B_ * S_) / 8, 256, 0, stream>>>(context, cov, attnf, gxall, watt,
                                                   w_t, wfold, whh_t, b_hh, out_cov, flags);
    }
}

// Round 8
// 602.997 us; speedup vs baseline: 1.2057x; 1.2057x over previous
//
#include <hip/hip_runtime.h>
#include <math.h>

typedef unsigned short ushort_t;
typedef __attribute__((ext_vector_type(8))) short short8;
typedef __attribute__((ext_vector_type(4))) float f32x4;
typedef __attribute__((ext_vector_type(4))) unsigned short ushort4v;

constexpr int B_ = 64, S_ = 512, DIM_ = 1024, COV_ = 256, TC_ = 768, KIH_ = 2049;
constexpr int NG_ = 1024, KG_ = 1280;  // gates GEMM: [32768 x KG] @ [KG x NG]

__device__ __forceinline__ float b2f(ushort_t u) {
    union { unsigned int i; float f; } v; v.i = ((unsigned int)u) << 16; return v.f;
}
__device__ __forceinline__ ushort_t f2b(float f) {
    unsigned int x = __float_as_uint(f);
    unsigned int r = x + 0x7fffu + ((x >> 16) & 1u);
    return (ushort_t)(r >> 16);
}
__device__ __forceinline__ float ldv(const float* p, size_t i) { return p[i]; }
__device__ __forceinline__ float ldv(const ushort_t* p, size_t i) { return b2f(p[i]); }

__device__ __forceinline__ float wave_reduce(float a) {
#pragma unroll
    for (int off = 32; off >= 1; off >>= 1) a += __shfl_down(a, off, 64);
    return a;
}

// 4x4 lane<->reg transpose within each 4-lane group (2 butterfly stages).
// In: lane (l&3)=g holds v[r] = T[g][r].  Out: lane (l&3)=q holds v[g] = T[g][q].
__device__ __forceinline__ void xpose4(f32x4& v, int l) {
    float s, r;
    s = (l & 1) ? v[0] : v[1]; r = __shfl_xor(s, 1, 64); if (l & 1) v[0] = r; else v[1] = r;
    s = (l & 1) ? v[2] : v[3]; r = __shfl_xor(s, 1, 64); if (l & 1) v[2] = r; else v[3] = r;
    s = (l & 2) ? v[0] : v[2]; r = __shfl_xor(s, 2, 64); if (l & 2) v[0] = r; else v[2] = r;
    s = (l & 2) ? v[1] : v[3]; r = __shfl_xor(s, 2, 64); if (l & 2) v[1] = r; else v[3] = r;
}

#define GLDS16(src, dst)                                                            \
    __builtin_amdgcn_global_load_lds(                                               \
        (const __attribute__((address_space(1))) void*)(src),                       \
        (__attribute__((address_space(3))) void*)(dst), 16, 0, 0)

// ---- dtype detection, parallel: 64-block partials + tiny combine --------------
// (was 1 block with a serial 128-iter HBM-latency chain = whole GPU idle ~25us)
__global__ __launch_bounds__(256) void k_detect_p(const unsigned char* __restrict__ mask,
                                                  const ushort_t* __restrict__ win,
                                                  int* __restrict__ parts) {
    __shared__ int r0[256];
    __shared__ int r1[256];
    int bid = blockIdx.x, tid = threadIdx.x, mb = 0, f32 = 0;
    for (int i = bid * 256 + tid; i < 32768; i += 64 * 256)
        if ((i & 3) != 0 && mask[i] != 0) mb = 1;
    for (int i = bid * 256 + tid; i < 32768; i += 64 * 256) {
        ushort_t u = win[2 * i];
        if ((u & 0x7F80u) >= 0x4480u) f32 = 1;
    }
    r0[tid] = mb; r1[tid] = f32; __syncthreads();
    for (int st = 128; st >= 1; st >>= 1) {
        if (tid < st) { r0[tid] |= r0[tid + st]; r1[tid] |= r1[tid + st]; }
        __syncthreads();
    }
    if (tid == 0) { parts[bid] = r0[0]; parts[64 + bid] = r1[0]; }
}
__global__ void k_detect_c(const int* __restrict__ parts, int* __restrict__ flags) {
    int tid = threadIdx.x;  // 64
    int a = parts[tid], b = parts[64 + tid];
#pragma unroll
    for (int off = 32; off >= 1; off >>= 1) {
        a |= __shfl_down(a, off, 64);
        b |= __shfl_down(b, off, 64);
    }
    if (tid == 0) { flags[0] = a; flags[1] = b; }
}

// ---- generic transpose -> canonical bf16: out[c*R+r] = in[r*ld+off+c] ---------
template <typename IT>
__device__ __forceinline__ void transpose_body(const IT* __restrict__ in,
                                               ushort_t* __restrict__ out,
                                               int R, int C, int ld, int off) {
    int idx = blockIdx.x * 256 + threadIdx.x;
    if (idx >= R * C) return;
    int r = idx / C, c = idx - r * C;
    out[c * R + r] = f2b(ldv(in, (size_t)r * ld + off + c));
}
__global__ void k_transpose(const void* __restrict__ in, ushort_t* __restrict__ out,
                            int R, int C, int ld, int off, const int* __restrict__ flags) {
    if (flags[1]) transpose_body((const float*)in, out, R, C, ld, off);
    else transpose_body((const ushort_t*)in, out, R, C, ld, off);
}

// ---- bfold[j] = sum_d bcov[d]*w_ih[j,d];  also writes watt[j] = w_ih[j,2048] --
template <typename IT>
__device__ __forceinline__ void bfold_body(const IT* __restrict__ bcov,
                                           const IT* __restrict__ wih,
                                           float* __restrict__ bfold,
                                           float* __restrict__ watt) {
    int j = blockIdx.x * 4 + (threadIdx.x >> 6);
    int lane = threadIdx.x & 63;
    const IT* wr = wih + (size_t)j * KIH_;
    float a = 0.f;
#pragma unroll
    for (int i = 0; i < 16; ++i) { int k = lane + 64 * i; a += ldv(bcov, k) * ldv(wr, k); }
    a = wave_reduce(a);
    if (lane == 0) { bfold[j] = a; watt[j] = ldv(wr, 2048); }
}
__global__ __launch_bounds__(256) void k_bfold(const void* __restrict__ bcov,
                                               const void* __restrict__ wih,
                                               float* __restrict__ bfold,
                                               float* __restrict__ watt,
                                               const int* __restrict__ flags) {
    if (flags[1]) bfold_body((const float*)bcov, (const float*)wih, bfold, watt);
    else bfold_body((const ushort_t*)bcov, (const ushort_t*)wih, bfold, watt);
}

// ---- wfold partials: wfp[p][c][j] = sum_{d in p*256..} W_cov[d,c]*w_ih[j,d] ---
// (was 1024-iter serial chain at 1 block/CU; now 4x blocks, 4x shorter chain)
__global__ __launch_bounds__(256) void k_wfold_p(const ushort_t* __restrict__ wcov_t,
                                                 const ushort_t* __restrict__ w_t,
                                                 float* __restrict__ wfp) {
    __shared__ float col[256];
    int c = blockIdx.x, p = blockIdx.y, tid = threadIdx.x;
    col[tid] = b2f(wcov_t[c * DIM_ + p * 256 + tid]);
    __syncthreads();
    float a0 = 0.f, a1 = 0.f, a2 = 0.f;
    const ushort_t* wt = w_t + (size_t)(p * 256) * TC_;
    for (int d = 0; d < 256; ++d) {
        float x = col[d];
        const ushort_t* wr = wt + d * TC_;
        a0 += x * b2f(wr[tid]);
        a1 += x * b2f(wr[tid + 256]);
        a2 += x * b2f(wr[tid + 512]);
    }
    float* o = wfp + ((size_t)p * COV_ + c) * TC_;
    o[tid] = a0;
    o[tid + 256] = a1;
    o[tid + 512] = a2;
}

// ---- legacy full wfold (only for the !fused fallback path) --------------------
__global__ __launch_bounds__(256) void k_wfold(const ushort_t* __restrict__ wcov_t,
                                               const ushort_t* __restrict__ w_t,
                                               float* __restrict__ wfold) {
    __shared__ float col[DIM_];
    int c = blockIdx.x, tid = threadIdx.x;
    for (int d = tid; d < DIM_; d += 256) col[d] = b2f(wcov_t[c * DIM_ + d]);
    __syncthreads();
    float a0 = 0.f, a1 = 0.f, a2 = 0.f;
    for (int d = 0; d < DIM_; ++d) {
        float x = col[d];
        const ushort_t* wr = w_t + d * TC_;
        a0 += x * b2f(wr[tid]);
        a1 += x * b2f(wr[tid + 256]);
        a2 += x * b2f(wr[tid + 512]);
    }
    wfold[c * TC_ + tid] = a0;
    wfold[c * TC_ + tid + 256] = a1;
    wfold[c * TC_ + tid + 512] = a2;
}

// ---- build Wg_t [NG=1024 rows][KG=1280 cols] bf16, GATE-INTERLEAVED -----------
// new row n = 4*c + g maps to old gate-major row j = g*256 + c.  Reads the 4
// wfold partials and sums them.
template <typename IT>
__device__ __forceinline__ void buildwg_body(const IT* __restrict__ wih,
                                             const IT* __restrict__ whh,
                                             const float* __restrict__ wfp,
                                             ushort_t* __restrict__ wg) {
    int idx = blockIdx.x * 256 + threadIdx.x;
    if (idx >= NG_ * KG_) return;
    int n = idx / KG_, k = idx - n * KG_;
    int g = n & 3, cq = n >> 2;
    int j = g * COV_ + cq;  // old row index in [0,1024)
    float v;
    if (k < DIM_) {
        v = (j < TC_) ? ldv(wih, (size_t)j * KIH_ + k) : 0.f;
    } else {
        int c = k - DIM_;
        float wf = 0.f;
        if (j < TC_) {
            size_t base = (size_t)c * TC_ + j;
            wf = wfp[base] + wfp[(size_t)COV_ * TC_ + base] +
                 wfp[2 * (size_t)COV_ * TC_ + base] + wfp[3 * (size_t)COV_ * TC_ + base];
        }
        if (j < 512)      v = wf + ldv(whh, (size_t)j * COV_ + c);
        else if (j < TC_) v = wf;
        else              v = ldv(whh, (size_t)(j - 256) * COV_ + c);
    }
    wg[(size_t)n * KG_ + k] = f2b(v);
}
__global__ void k_buildwg(const void* __restrict__ wih, const void* __restrict__ whh,
                          const float* __restrict__ wfp, ushort_t* __restrict__ wg,
                          const int* __restrict__ flags) {
    if (flags[1]) buildwg_body((const float*)wih, (const float*)whh, wfp, wg);
    else buildwg_body((const ushort_t*)wih, (const ushort_t*)whh, wfp, wg);
}

// ---- target = h @ W_in^T (wave per output) ------------------------------------
template <typename IT>
__device__ __forceinline__ void target_body(const IT* __restrict__ h,
                                            const IT* __restrict__ W_in,
                                            float* __restrict__ target) {
    int o = blockIdx.x * 4 + (threadIdx.x >> 6);
    int lane = threadIdx.x & 63;
    int b = o >> 10, d = o & (DIM_ - 1);
    const IT* hr = h + (size_t)b * DIM_;
    const IT* wr = W_in + (size_t)d * DIM_;
    float a = 0.f;
#pragma unroll
    for (int j = 0; j < 16; ++j) { int k = lane + 64 * j; a += ldv(hr, k) * ldv(wr, k); }
    a = wave_reduce(a);
    if (lane == 0) target[o] = a;
}
__global__ __launch_bounds__(256) void k_target_w(const void* __restrict__ h,
                                                  const void* __restrict__ W_in,
                                                  float* __restrict__ target,
                                                  const int* __restrict__ flags) {
    if (flags[1]) target_body((const float*)h, (const float*)W_in, target);
    else target_body((const ushort_t*)h, (const ushort_t*)W_in, target);
}

// ---- mvec[b,c] = sum_d target[b,d]*W_cov[d,c];  bct[b] = sum_d target*b_cov ---
// grid (B, 4): block (b,q) does channels q*64..q*64+63; 64 ch x 4 d-groups.
template <typename IT>
__device__ __forceinline__ void mvec_body(const float* __restrict__ target,
                                          const IT* __restrict__ W_cov,
                                          const IT* __restrict__ bcov,
                                          float* __restrict__ mvec,
                                          float* __restrict__ bct) {
    __shared__ float tg[DIM_];
    __shared__ float red[256];
    int b = blockIdx.x, q = blockIdx.y, tid = threadIdx.x;
    float pb = 0.f;
    for (int k = tid; k < DIM_; k += 256) {
        float t = target[b * DIM_ + k];
        tg[k] = t; pb += t * ldv(bcov, k);
    }
    red[tid] = pb; __syncthreads();
    for (int st = 128; st >= 1; st >>= 1) {
        if (tid < st) red[tid] += red[tid + st];
        __syncthreads();
    }
    if (q == 0 && tid == 0) bct[b] = red[0];
    __syncthreads();  // red[0] read complete before red is reused below
    int cg = tid & 63, dg = tid >> 6;
    int c = q * 64 + cg;
    float acc = 0.f;
    int d0 = dg * 256;
    for (int d = d0; d < d0 + 256; ++d) acc += tg[d] * ldv(W_cov, (size_t)d * COV_ + c);
    red[dg * 64 + cg] = acc;
    __syncthreads();
    if (dg == 0)
        mvec[b * COV_ + c] = red[cg] + red[64 + cg] + red[128 + cg] + red[192 + cg];
}
__global__ __launch_bounds__(256) void k_mvec(const float* __restrict__ target,
                                              const void* __restrict__ W_cov,
                                              const void* __restrict__ bcov,
                                              float* __restrict__ mvec,
                                              float* __restrict__ bct,
                                              const int* __restrict__ flags) {
    if (flags[1]) mvec_body(target, (const float*)W_cov, (const float*)bcov, mvec, bct);
    else mvec_body(target, (const ushort_t*)W_cov, (const ushort_t*)bcov, mvec, bct);
}

// ---- raw scores + fused f32->bf16 conversion ----------------------------------
// grid (B, 16): 8 rows per wave (was 16) -> 2x blocks for latency hiding.
template <typename IT>
__device__ __forceinline__ void scoreraw_body(const IT* __restrict__ context,
                                              const IT* __restrict__ cov,
                                              const float* __restrict__ target,
                                              const float* __restrict__ mvec,
                                              const float* __restrict__ bct,
                                              float* __restrict__ scf,
                                              ushort_t* __restrict__ ctx_bf,
                                              ushort_t* __restrict__ cov_bf) {
    __shared__ float tg[DIM_];
    __shared__ float ms[COV_];
    int b = blockIdx.x, tid = threadIdx.x;
    for (int k = tid; k < DIM_; k += 256) tg[k] = target[b * DIM_ + k];
    if (tid < COV_) ms[tid] = mvec[b * COV_ + tid];
    float bc = bct[b];
    __syncthreads();
    int wave = tid >> 6, lane = tid & 63;
    int s0 = blockIdx.y * 32 + wave * 8;
    for (int i = 0; i < 8; ++i) {
        int s = s0 + i;
        size_t row = (size_t)(b * S_ + s);
        const IT* cr = context + row * DIM_;
        const IT* vr = cov + row * COV_;
        float a = 0.f;
        if constexpr (sizeof(IT) == 4) {
#pragma unroll
            for (int j = 0; j < 4; ++j) {
                int d = lane * 4 + 256 * j;
                float4 x = *(const float4*)((const float*)cr + d);
                a += x.x * tg[d] + x.y * tg[d + 1] + x.z * tg[d + 2] + x.w * tg[d + 3];
                if (ctx_bf) {
                    ushort4v u;
                    u[0] = f2b(x.x); u[1] = f2b(x.y); u[2] = f2b(x.z); u[3] = f2b(x.w);
                    *(ushort4v*)(ctx_bf + row * DIM_ + d) = u;
                }
            }
            {
                int cc = lane * 4;
                float4 x = *(const float4*)((const float*)vr + cc);
                a += x.x * ms[cc] + x.y * ms[cc + 1] + x.z * ms[cc + 2] + x.w * ms[cc + 3];
                if (cov_bf) {
                    ushort4v u;
                    u[0] = f2b(x.x); u[1] = f2b(x.y); u[2] = f2b(x.z); u[3] = f2b(x.w);
                    *(ushort4v*)(cov_bf + row * COV_ + cc) = u;
                }
            }
        } else {
#pragma unroll
            for (int j = 0; j < 16; ++j) { int d = lane + 64 * j; a += ldv(cr, d) * tg[d]; }
#pragma unroll
            for (int j = 0; j < 4; ++j) { int c = lane + 64 * j; a += ldv(vr, c) * ms[c]; }
        }
        a = wave_reduce(a);
        if (lane == 0) scf[row] = a + bc;
    }
}
__global__ __launch_bounds__(256) void k_scoreraw(const void* __restrict__ context,
                                                  const void* __restrict__ cov,
                                                  const float* __restrict__ target,
                                                  const float* __restrict__ mvec,
                                                  const float* __restrict__ bct,
                                                  float* __restrict__ scf,
                                                  ushort_t* __restrict__ ctx_bf,
                                                  ushort_t* __restrict__ cov_bf,
                                                  const int* __restrict__ flags) {
    if (flags[1]) scoreraw_body((const float*)context, (const float*)cov, target, mvec, bct,
                                scf, ctx_bf, cov_bf);
    else scoreraw_body((const ushort_t*)context, (const ushort_t*)cov, target, mvec, bct,
                       scf, ctx_bf, cov_bf);
}

// ---- masked softmax over scf --------------------------------------------------
__global__ __launch_bounds__(256) void k_softmax(const float* __restrict__ scf,
                                                 const void* __restrict__ maskp,
                                                 const int* __restrict__ flags,
                                                 float* __restrict__ attnf,
                                                 float* __restrict__ attn_out) {
    __shared__ float red[256];
    int b = blockIdx.x, tid = threadIdx.x;
    int mb = flags[0];
    int i0 = b * S_ + tid, i1 = i0 + 256;
    int m0 = mb ? (int)((const unsigned char*)maskp)[i0] : ((const int*)maskp)[i0];
    int m1 = mb ? (int)((const unsigned char*)maskp)[i1] : ((const int*)maskp)[i1];
    float s0 = m0 ? -INFINITY : scf[i0];
    float s1 = m1 ? -INFINITY : scf[i1];
    red[tid] = fmaxf(s0, s1); __syncthreads();
    for (int st = 128; st >= 1; st >>= 1) {
        if (tid < st) red[tid] = fmaxf(red[tid], red[tid + st]);
        __syncthreads();
    }
    float mx = red[0]; __syncthreads();
    float e0 = expf(s0 - mx), e1 = expf(s1 - mx);
    red[tid] = e0 + e1; __syncthreads();
    for (int st = 128; st >= 1; st >>= 1) {
        if (tid < st) red[tid] += red[tid + st];
        __syncthreads();
    }
    float inv = 1.0f / red[0];
    float a0 = e0 * inv, a1 = e1 * inv;
    attnf[i0] = a0; attnf[i1] = a1;
    attn_out[i0] = a0; attn_out[i1] = a1;
}

// ---- wc partials (bf16 inputs): grid (B, 16); each block sums 32 s-rows -------
__global__ __launch_bounds__(256) void k_wcpart2(const ushort_t* __restrict__ ctx_bf,
                                                 const ushort_t* __restrict__ cov_bf,
                                                 const void* __restrict__ ctx_in,
                                                 const void* __restrict__ cov_in,
                                                 const float* __restrict__ attnf,
                                                 float* __restrict__ wcp,
                                                 float* __restrict__ acp,
                                                 const int* __restrict__ flags) {
    const ushort_t* C = flags[1] ? ctx_bf : (const ushort_t*)ctx_in;
    const ushort_t* V = flags[1] ? cov_bf : (const ushort_t*)cov_in;
    __shared__ float at[32];
    int b = blockIdx.x, ch = blockIdx.y, tid = threadIdx.x;
    int s0 = ch * 32;
    if (tid < 32) at[tid] = attnf[b * S_ + s0 + tid];
    __syncthreads();
    float acv = 0.f;
    for (int s = 0; s < 32; ++s)
        acv += at[s] * b2f(V[((size_t)(b * S_ + s0 + s)) * COV_ + tid]);
    acp[((size_t)ch * B_ + b) * COV_ + tid] = acv;
    float acc[4] = {0.f, 0.f, 0.f, 0.f};
    for (int s = 0; s < 32; ++s) {
        float w = at[s];
        const ushort_t* cr = C + ((size_t)(b * S_ + s0 + s)) * DIM_;
        acc[0] += w * b2f(cr[tid]);
        acc[1] += w * b2f(cr[tid + 256]);
        acc[2] += w * b2f(cr[tid + 512]);
        acc[3] += w * b2f(cr[tid + 768]);
    }
    size_t base = ((size_t)ch * B_ + b) * DIM_;
    for (int m = 0; m < 4; ++m) wcp[base + tid + 256 * m] = acc[m];
}

// ---- wc final: reduce 16 partials + ac@W_cov^T + b_cov ------------------------
template <typename IT>
__device__ __forceinline__ void wcfin_body(const float* __restrict__ wcp,
                                           const float* __restrict__ acp,
                                           const ushort_t* __restrict__ wcov_t,
                                           const IT* __restrict__ bcov,
                                           float* __restrict__ wc) {
    __shared__ float ac[COV_];
    int b = blockIdx.x, tid = threadIdx.x;
    float a = 0.f;
    for (int ch = 0; ch < 16; ++ch) a += acp[((size_t)ch * B_ + b) * COV_ + tid];
    ac[tid] = a;
    __syncthreads();
    float acc[4] = {0.f, 0.f, 0.f, 0.f};
    for (int ch = 0; ch < 16; ++ch) {
        size_t base = ((size_t)ch * B_ + b) * DIM_;
        for (int m = 0; m < 4; ++m) acc[m] += wcp[base + tid + 256 * m];
    }
    for (int c = 0; c < COV_; ++c) {
        float av = ac[c];
        const ushort_t* wr = wcov_t + c * DIM_;
        acc[0] += av * b2f(wr[tid]);
        acc[1] += av * b2f(wr[tid + 256]);
        acc[2] += av * b2f(wr[tid + 512]);
        acc[3] += av * b2f(wr[tid + 768]);
    }
    for (int m = 0; m < 4; ++m) {
        int d = tid + 256 * m;
        wc[b * DIM_ + d] = acc[m] + ldv(bcov, d);
    }
}
__global__ __launch_bounds__(256) void k_wcfin(const float* __restrict__ wcp,
                                               const float* __restrict__ acp,
                                               const ushort_t* __restrict__ wcov_t,
                                               const void* __restrict__ bcov,
                                               float* __restrict__ wc,
                                               const int* __restrict__ flags) {
    if (flags[1]) wcfin_body(wcp, acp, wcov_t, (const float*)bcov, wc);
    else wcfin_body(wcp, acp, wcov_t, (const ushort_t*)bcov, wc);
}

// ---- h_tilde = tanh([wc, h] @ W_out^T) (wave per output) ----------------------
template <typename IT>
__device__ __forceinline__ void htilde_body(const float* __restrict__ wc,
                                            const IT* __restrict__ h,
                                            const IT* __restrict__ W_out,
                                            float* __restrict__ out_ht) {
    int o = blockIdx.x * 4 + (threadIdx.x >> 6);
    int lane = threadIdx.x & 63;
    int b = o >> 10, d = o & (DIM_ - 1);
    const float* wcr = wc + b * DIM_;
    const IT* hr = h + (size_t)b * DIM_;
    const IT* wr = W_out + (size_t)d * 2 * DIM_;
    float a = 0.f;
#pragma unroll
    for (int j = 0; j < 16; ++j) { int k = lane + 64 * j; a += wcr[k] * ldv(wr, k); }
#pragma unroll
    for (int j = 0; j < 16; ++j) { int k = lane + 64 * j; a += ldv(hr, k) * ldv(wr, DIM_ + k); }
    a = wave_reduce(a);
    if (lane == 0) out_ht[o] = tanhf(a);
}
__global__ __launch_bounds__(256) void k_htilde_w(const float* __restrict__ wc,
                                                  const void* __restrict__ h,
                                                  const void* __restrict__ W_out,
                                                  float* __restrict__ out_ht,
                                                  const int* __restrict__ flags) {
    if (flags[1]) htilde_body(wc, (const float*)h, (const float*)W_out, out_ht);
    else htilde_body(wc, (const ushort_t*)h, (const ushort_t*)W_out, out_ht);
}

// ---- gxall[b,j] = b_ih[j] + bfold[j] + sum_k h[b,k]*w_ih[j,1024+k] ------------
template <typename IT>
__device__ __forceinline__ void gxh_body(const IT* __restrict__ h,
                                         const IT* __restrict__ w_ih,
                                         const IT* __restrict__ b_ih,
                                         const float* __restrict__ bfold,
                                         float* __restrict__ gxall) {
    int o = blockIdx.x * 4 + (threadIdx.x >> 6);
    int lane = threadIdx.x & 63;
    int b = o / TC_, j = o - b * TC_;
    const IT* hr = h + (size_t)b * DIM_;
    const IT* wr = w_ih + (size_t)j * KIH_ + DIM_;
    float a = 0.f;
#pragma unroll
    for (int i = 0; i < 16; ++i) { int k = lane + 64 * i; a += ldv(hr, k) * ldv(wr, k); }
    a = wave_reduce(a);
    if (lane == 0) gxall[o] = a + ldv(b_ih, j) + bfold[j];
}
__global__ __launch_bounds__(256) void k_gxh_w(const void* __restrict__ h,
                                               const void* __restrict__ w_ih,
                                               const void* __restrict__ b_ih,
                                               const float* __restrict__ bfold,
                                               float* __restrict__ gxall,
                                               const int* __restrict__ flags) {
    if (flags[1]) gxh_body((const float*)h, (const float*)w_ih, (const float*)b_ih, bfold, gxall);
    else gxh_body((const ushort_t*)h, (const ushort_t*)w_ih, (const ushort_t*)b_ih, bfold, gxall);
}

// ---- MFMA gates GEMM v6: BK=64 (2x work per barrier) + unroll-2 dbuf ----------
// (unchanged from round 6: 125us, MfmaUtil 29%.  Serves as the control while
// the serial prep-kernel chain is parallelized.)
__global__ __launch_bounds__(256) void k_gemm6(const ushort_t* __restrict__ ctx_bf,
                                               const ushort_t* __restrict__ cov_bf,
                                               const void* __restrict__ ctx_in,
                                               const void* __restrict__ cov_in,
                                               const ushort_t* __restrict__ wg,
                                               const float* __restrict__ attnf,
                                               const float* __restrict__ gxall,
                                               const float* __restrict__ watt,
                                               const void* __restrict__ bhh,
                                               float* __restrict__ out_cov,
                                               const int* __restrict__ flags) {
    const int f32in = flags[1];
    const ushort_t* Xc = f32in ? ctx_bf : (const ushort_t*)ctx_in;
    const ushort_t* Xv = f32in ? cov_bf : (const ushort_t*)cov_in;
    __shared__ __align__(16) unsigned char smem[65536];
    ushort_t* A0 = (ushort_t*)smem;
    ushort_t* B0 = A0 + 8192;
    ushort_t* A1 = B0 + 8192;
    ushort_t* B1 = A1 + 8192;
    float* smN = (float*)smem;            // [128][33]
    float* smZ = smN + 128 * 33;          // [128][33]

    int tid = threadIdx.x;
    int p = blockIdx.x;
    int xcd = p & 7, t = p >> 3;
    int nb = t & 7, rb = xcd + 8 * (t >> 3);
    int n0 = nb * 128;
    int grow0 = rb * 128;
    int wave = tid >> 6, lane = tid & 63;
    int wm = wave >> 1, wn = wave & 1;
    int half = lane >> 4, r16 = lane & 15;

    const ushort_t* gAc[4]; const ushort_t* gAv[4]; const ushort_t* gB[4];
    int ldsOff[4];
#pragma unroll
    for (int j = 0; j < 4; ++j) {
        int c = wave * 256 + j * 64 + lane;
        int row = c >> 3, sl = (c & 7) ^ ((c >> 3) & 7);
        gAc[j] = Xc + (size_t)(grow0 + row) * DIM_ + sl * 8;
        gAv[j] = Xv + (size_t)(grow0 + row) * COV_ + sl * 8;
        gB[j]  = wg + (size_t)(n0 + row) * KG_ + sl * 8;
        ldsOff[j] = (wave * 256 + j * 64) * 8;
    }

    int offA[2][4], offB[2][4];
#pragma unroll
    for (int kh = 0; kh < 2; ++kh)
#pragma unroll
        for (int u = 0; u < 4; ++u) {
            int rA = wm * 64 + u * 16 + r16;
            offA[kh][u] = rA * 64 + ((kh * 4 + half) ^ (rA & 7)) * 8;
            int rB = wn * 64 + u * 16 + r16;
            offB[kh][u] = rB * 64 + ((kh * 4 + half) ^ (rB & 7)) * 8;
        }

    f32x4 acc[4][4];
#pragma unroll
    for (int i = 0; i < 4; ++i)
#pragma unroll
        for (int j = 0; j < 4; ++j) acc[i][j] = (f32x4){0.f, 0.f, 0.f, 0.f};

    auto stage = [&](int kt, ushort_t* Ad, ushort_t* Bd) {
        int k0 = kt * 64;
        if (k0 < DIM_) {
#pragma unroll
            for (int j = 0; j < 4; ++j) GLDS16(gAc[j] + k0, Ad + ldsOff[j]);
        } else {
            int kk = k0 - DIM_;
#pragma unroll
            for (int j = 0; j < 4; ++j) GLDS16(gAv[j] + kk, Ad + ldsOff[j]);
        }
#pragma unroll
        for (int j = 0; j < 4; ++j) GLDS16(gB[j] + k0, Bd + ldsOff[j]);
    };
    auto compute = [&](const ushort_t* Ac, const ushort_t* Bc) {
#pragma unroll
        for (int kh = 0; kh < 2; ++kh) {
            short8 a[4], b[4];
#pragma unroll
            for (int u = 0; u < 4; ++u) a[u] = *(const short8*)&Ac[offA[kh][u]];
#pragma unroll
            for (int u = 0; u < 4; ++u) b[u] = *(const short8*)&Bc[offB[kh][u]];
#pragma unroll
            for (int i = 0; i < 4; ++i)
#pragma unroll
                for (int j = 0; j < 4; ++j)
                    acc[i][j] = __builtin_amdgcn_mfma_f32_16x16x32_bf16(a[i], b[j], acc[i][j], 0, 0, 0);
        }
    };

    constexpr int NT = KG_ / 64;  // 20 (even)
    stage(0, A0, B0);
    __syncthreads();
#pragma unroll 1
    for (int kt = 0; kt < NT; kt += 2) {
        stage(kt + 1, A1, B1);
        compute(A0, B0);
        __syncthreads();
        if (kt + 2 < NT) stage(kt + 2, A0, B0);
        compute(A1, B1);
        __syncthreads();
    }

    // ---- fused GRU epilogue ----
    int l = lane;
    int bb = grow0 >> 9;
    const float* gx = gxall + bb * TC_;
    int rloc[4]; float atv[4];
#pragma unroll
    for (int i = 0; i < 4; ++i) {
        rloc[i] = wm * 64 + 16 * i + ((l >> 4) << 2) + (l & 3);
        atv[i] = attnf[grow0 + rloc[i]];
    }
#pragma unroll
    for (int j = 0; j < 4; ++j) {
        int cl = wn * 16 + 4 * j + ((l >> 2) & 3);
        int c = (n0 >> 2) + cl;
        float gxR = gx[c], gxZ = gx[COV_ + c], gxN = gx[2 * COV_ + c];
        float waR = watt[c], waZ = watt[COV_ + c], waN = watt[2 * COV_ + c];
        float bhR, bhZ, bhN;
        if (f32in) {
            const float* bp = (const float*)bhh;
            bhR = bp[c]; bhZ = bp[COV_ + c]; bhN = bp[2 * COV_ + c];
        } else {
            const ushort_t* bp = (const ushort_t*)bhh;
            bhR = b2f(bp[c]); bhZ = b2f(bp[COV_ + c]); bhN = b2f(bp[2 * COV_ + c]);
        }
#pragma unroll
        for (int i = 0; i < 4; ++i) {
            f32x4 v = acc[i][j];
            xpose4(v, l);
            float at = atv[i];
            float aR  = v[0] + gxR + at * waR + bhR;
            float aZ  = v[1] + gxZ + at * waZ + bhZ;
            float aXN = v[2] + gxN + at * waN;
            float aHN = v[3] + bhN;
            float r = 1.f / (1.f + expf(-aR));
            float z = 1.f / (1.f + expf(-aZ));
            float nn = tanhf(aXN + r * aHN);
            smN[rloc[i] * 33 + cl] = nn;
            smZ[rloc[i] * 33 + cl] = z;
        }
    }
    __syncthreads();
    int cbase = nb * 32;
    for (int u = tid; u < 128 * 8; u += 256) {
        int rl = u >> 3, c4 = (u & 7) * 4;
        float n0v = smN[rl * 33 + c4 + 0], n1v = smN[rl * 33 + c4 + 1];
        float n2v = smN[rl * 33 + c4 + 2], n3v = smN[rl * 33 + c4 + 3];
        float z0 = smZ[rl * 33 + c4 + 0], z1 = smZ[rl * 33 + c4 + 1];
        float z2 = smZ[rl * 33 + c4 + 2], z3 = smZ[rl * 33 + c4 + 3];
        size_t base = (size_t)(grow0 + rl) * COV_ + cbase + c4;
        float h0v, h1v, h2v, h3v;
        if (f32in) {
            float4 hv = *(const float4*)((const float*)cov_in + base);
            h0v = hv.x; h1v = hv.y; h2v = hv.z; h3v = hv.w;
        } else {
            ushort4v hv = *(const ushort4v*)((const ushort_t*)cov_in + base);
            h0v = b2f(hv[0]); h1v = b2f(hv[1]); h2v = b2f(hv[2]); h3v = b2f(hv[3]);
        }
        float4 o;
        o.x = (1.f - z0) * n0v + z0 * h0v;
        o.y = (1.f - z1) * n1v + z1 * h1v;
        o.z = (1.f - z2) * n2v + z2 * h2v;
        o.w = (1.f - z3) * n3v + z3 * h3v;
        *(float4*)(out_cov + base) = o;
    }
}

// ---- legacy GRU (fallback when ws too small) ----------------------------------
template <typename IT>
__device__ __forceinline__ void gru_body(const IT* __restrict__ context,
                                         const IT* __restrict__ cov,
                                         const float* __restrict__ attnf,
                                         const float* __restrict__ gxall,
                                         const float* __restrict__ watt,
                                         const ushort_t* __restrict__ w_t,
                                         const float* __restrict__ wfold,
                                         const ushort_t* __restrict__ whh_t,
                                         const IT* __restrict__ bhh,
                                         float* __restrict__ out_cov) {
    __shared__ float xc[8][DIM_];
    __shared__ float h0s[8][COV_];
    __shared__ float atn[8];
    int base = blockIdx.x * 8, tid = threadIdx.x;
    int b = base / S_;
    for (int i = tid; i < 8 * DIM_; i += 256)
        ((float*)xc)[i] = ldv(context, (size_t)base * DIM_ + i);
    for (int i = tid; i < 8 * COV_; i += 256)
        ((float*)h0s)[i] = ldv(cov, (size_t)base * COV_ + i);
    if (tid < 8) atn[tid] = attnf[base + tid];
    __syncthreads();
    int c = tid;
    float gxR = gxall[b * TC_ + c], gxZ = gxall[b * TC_ + 256 + c], gxN = gxall[b * TC_ + 512 + c];
    float bhR = ldv(bhh, c), bhZ = ldv(bhh, 256 + c), bhN = ldv(bhh, 512 + c);
    float waR = watt[c], waZ = watt[256 + c], waN = watt[512 + c];
    float aR[8], aZ[8], aXN[8], aHN[8];
#pragma unroll
    for (int g = 0; g < 8; ++g) {
        float a = atn[g];
        aR[g] = gxR + bhR + a * waR;
        aZ[g] = gxZ + bhZ + a * waZ;
        aXN[g] = gxN + a * waN;
        aHN[g] = bhN;
    }
    for (int k = 0; k < DIM_; ++k) {
        const ushort_t* row = w_t + k * TC_;
        float wr = b2f(row[c]), wz = b2f(row[256 + c]), wn = b2f(row[512 + c]);
#pragma unroll
        for (int g = 0; g < 8; ++g) {
            float x = xc[g][k];
            aR[g] += x * wr; aZ[g] += x * wz; aXN[g] += x * wn;
        }
    }
    for (int k = 0; k < COV_; ++k) {
        const float* row = wfold + k * TC_;
        float wr = row[c], wz = row[256 + c], wn = row[512 + c];
#pragma unroll
        for (int g = 0; g < 8; ++g) {
            float x = h0s[g][k];
            aR[g] += x * wr; aZ[g] += x * wz; aXN[g] += x * wn;
        }
    }
    for (int k = 0; k < COV_; ++k) {
        const ushort_t* row = whh_t + k * TC_;
        float wr = b2f(row[c]), wz = b2f(row[256 + c]), wn = b2f(row[512 + c]);
#pragma unroll
        for (int g = 0; g < 8; ++g) {
            float hh = h0s[g][k];
            aR[g] += hh * wr; aZ[g] += hh * wz; aHN[g] += hh * wn;
        }
    }
#pragma unroll
    for (int g = 0; g < 8; ++g) {
        float r = 1.f / (1.f + expf(-aR[g]));
        float z = 1.f / (1.f + expf(-aZ[g]));
        float n = tanhf(aXN[g] + r * aHN[g]);
        float h0c = h0s[g][c];
        out_cov[(size_t)(base + g) * COV_ + c] = (1.f - z) * n + z * h0c;
    }
}
__global__ __launch_bounds__(256) void k_gru_f(const void* __restrict__ context,
                                               const void* __restrict__ cov,
                                               const float* __restrict__ attnf,
                                               const float* __restrict__ gxall,
                                               const float* __restrict__ watt,
                                               const ushort_t* __restrict__ w_t,
                                               const float* __restrict__ wfold,
                                               const ushort_t* __restrict__ whh_t,
                                               const void* __restrict__ bhh,
                                               float* __restrict__ out_cov,
                                               const int* __restrict__ flags) {
    if (flags[1]) gru_body((const float*)context, (const float*)cov, attnf, gxall, watt,
                           w_t, wfold, whh_t, (const float*)bhh, out_cov);
    else gru_body((const ushort_t*)context, (const ushort_t*)cov, attnf, gxall, watt,
                  w_t, wfold, whh_t, (const ushort_t*)bhh, out_cov);
}

extern "C" void kernel_launch(void* const* d_in, const int* in_sizes, int n_in,
                              void* d_out, int out_size, void* d_ws, size_t ws_size,
                              hipStream_t stream) {
    const void* h       = d_in[0];
    const void* context = d_in[1];
    const void* cov     = d_in[2];
    const void* W_in    = d_in[3];
    const void* W_out   = d_in[4];
    const void* W_cov   = d_in[5];
    const void* b_cov   = d_in[6];
    const void* w_ih    = d_in[7];
    const void* w_hh    = d_in[8];
    const void* b_ih    = d_in[9];
    const void* b_hh    = d_in[10];
    const void* maskp   = d_in[11];

    float* out = (float*)d_out;
    float* out_ht   = out;
    float* out_attn = out + B_ * DIM_;
    float* out_cov  = out + B_ * DIM_ + B_ * S_;

    char* ws = (char*)d_ws;
    size_t o = 0;
    float* target = (float*)(ws + o); o += (size_t)B_ * DIM_ * 4;
    float* attnf  = (float*)(ws + o); o += (size_t)B_ * S_ * 4;
    float* wc     = (float*)(ws + o); o += (size_t)B_ * DIM_ * 4;
    float* gxall  = (float*)(ws + o); o += (size_t)B_ * TC_ * 4;
    float* watt   = (float*)(ws + o); o += 4096;
    float* mvec   = (float*)(ws + o); o += (size_t)B_ * COV_ * 4;
    float* bct    = (float*)(ws + o); o += 4096;
    float* bfold  = (float*)(ws + o); o += 4096;
    float* wfold  = (float*)(ws + o); o += (size_t)COV_ * TC_ * 4;
    float* wfp    = (float*)(ws + o); o += (size_t)4 * COV_ * TC_ * 4;  // 3 MB partials
    int* dparts   = (int*)(ws + o);   o += 512;
    ushort_t* w_t    = (ushort_t*)(ws + o); o += (size_t)DIM_ * TC_ * 2;
    ushort_t* whh_t  = (ushort_t*)(ws + o); o += (size_t)COV_ * TC_ * 2;
    ushort_t* wcov_t = (ushort_t*)(ws + o); o += (size_t)COV_ * DIM_ * 2;
    int* flags = (int*)(ws + o); o += 256;
    float* scf   = (float*)(ws + o); o += (size_t)B_ * S_ * 4;
    float* wcp   = (float*)(ws + o); o += (size_t)16 * B_ * DIM_ * 4;  // 4 MB
    float* acp   = (float*)(ws + o); o += (size_t)16 * B_ * COV_ * 4;  // 1 MB
    ushort_t* wg = (ushort_t*)(ws + o); o += (size_t)NG_ * KG_ * 2;
    ushort_t* ctx_bf = (ushort_t*)(ws + o); o += (size_t)B_ * S_ * DIM_ * 2;  // 67 MB
    ushort_t* cov_bf = (ushort_t*)(ws + o); o += (size_t)B_ * S_ * COV_ * 2;  // 17 MB
    size_t fixed = o;

    const size_t TOTAL_ROWS = (size_t)B_ * S_;  // 32768
    const bool fused = ws_size >= fixed;

    // dtype detection (parallel) + weight prep
    k_detect_p<<<64, 256, 0, stream>>>((const unsigned char*)maskp, (const ushort_t*)W_in, dparts);
    k_detect_c<<<1, 64, 0, stream>>>(dparts, flags);
    k_transpose<<<(TC_ * DIM_) / 256, 256, 0, stream>>>(w_ih, w_t, TC_, DIM_, KIH_, 0, flags);
    k_transpose<<<(DIM_ * COV_) / 256, 256, 0, stream>>>(W_cov, wcov_t, DIM_, COV_, COV_, 0, flags);
    if (!fused)
        k_transpose<<<(TC_ * COV_) / 256, 256, 0, stream>>>(w_hh, whh_t, TC_, COV_, COV_, 0, flags);
    k_bfold<<<TC_ / 4, 256, 0, stream>>>(b_cov, w_ih, bfold, watt, flags);
    if (fused) {
        k_wfold_p<<<dim3(COV_, 4), 256, 0, stream>>>(wcov_t, w_t, wfp);
        k_buildwg<<<(NG_ * KG_ + 255) / 256, 256, 0, stream>>>(w_ih, w_hh, wfp, wg, flags);
    } else {
        k_wfold<<<COV_, 256, 0, stream>>>(wcov_t, w_t, wfold);
    }

    // attention path (scoreraw also emits the bf16 copies of ctx/cov)
    k_target_w<<<(B_ * DIM_) / 4, 256, 0, stream>>>(h, W_in, target, flags);
    k_mvec<<<dim3(B_, 4), 256, 0, stream>>>(target, W_cov, b_cov, mvec, bct, flags);
    k_scoreraw<<<dim3(B_, 16), 256, 0, stream>>>(context, cov, target, mvec, bct, scf,
                                                 fused ? ctx_bf : nullptr,
                                                 fused ? cov_bf : nullptr, flags);
    k_softmax<<<B_, 256, 0, stream>>>(scf, maskp, flags, attnf, out_attn);
    if (fused)
        k_wcpart2<<<dim3(B_, 16), 256, 0, stream>>>(ctx_bf, cov_bf, context, cov, attnf,
                                                    wcp, acp, flags);
    else
        k_wcpart2<<<dim3(B_, 16), 256, 0, stream>>>((const ushort_t*)context, (const ushort_t*)cov,
                                                    context, cov, attnf, wcp, acp, flags);
    k_wcfin<<<B_, 256, 0, stream>>>(wcp, acp, wcov_t, b_cov, wc, flags);
    k_htilde_w<<<(B_ * DIM_) / 4, 256, 0, stream>>>(wc, h, W_out, out_ht, flags);

    // GRU coverage path (single fused GEMM+activation)
    k_gxh_w<<<(B_ * TC_) / 4, 256, 0, stream>>>(h, w_ih, b_ih, bfold, gxall, flags);
    if (fused) {
        int nblk = (int)(TOTAL_ROWS / 128) * (NG_ / 128);  // 2048
        k_gemm6<<<nblk, 256, 0, stream>>>(ctx_bf, cov_bf, context, cov, wg, attnf,
                                          gxall, watt, b_hh, out_cov, flags);
    } else {
        k_gru_f<<<(B_ * S_) / 8, 256, 0, stream>>>(context, cov, attnf, gxall, watt,
                                                   w_t, wfold, whh_t, b_hh, out_cov, flags);
    }
}

// Round 9
// 602.719 us; speedup vs baseline: 1.2062x; 1.0005x over previous
//
#include <hip/hip_runtime.h>
#include <math.h>

typedef unsigned short ushort_t;
typedef __attribute__((ext_vector_type(8))) short short8;
typedef __attribute__((ext_vector_type(4))) float f32x4;
typedef __attribute__((ext_vector_type(4))) unsigned short ushort4v;

constexpr int B_ = 64, S_ = 512, DIM_ = 1024, COV_ = 256, TC_ = 768, KIH_ = 2049;
constexpr int NG_ = 1024, KG_ = 1280;  // gates GEMM: [32768 x KG] @ [KG x NG]

__device__ __forceinline__ float b2f(ushort_t u) {
    union { unsigned int i; float f; } v; v.i = ((unsigned int)u) << 16; return v.f;
}
__device__ __forceinline__ ushort_t f2b(float f) {
    unsigned int x = __float_as_uint(f);
    unsigned int r = x + 0x7fffu + ((x >> 16) & 1u);
    return (ushort_t)(r >> 16);
}
__device__ __forceinline__ float ldv(const float* p, size_t i) { return p[i]; }
__device__ __forceinline__ float ldv(const ushort_t* p, size_t i) { return b2f(p[i]); }

// unaligned-safe float4 load (w_ih rows have odd stride 2049)
__device__ __forceinline__ f32x4 ld4u(const float* p) {
    f32x4 v; __builtin_memcpy(&v, p, 16); return v;
}

__device__ __forceinline__ float wave_reduce(float a) {
#pragma unroll
    for (int off = 32; off >= 1; off >>= 1) a += __shfl_down(a, off, 64);
    return a;
}

// 4x4 lane<->reg transpose within each 4-lane group (2 butterfly stages).
__device__ __forceinline__ void xpose4(f32x4& v, int l) {
    float s, r;
    s = (l & 1) ? v[0] : v[1]; r = __shfl_xor(s, 1, 64); if (l & 1) v[0] = r; else v[1] = r;
    s = (l & 1) ? v[2] : v[3]; r = __shfl_xor(s, 1, 64); if (l & 1) v[2] = r; else v[3] = r;
    s = (l & 2) ? v[0] : v[2]; r = __shfl_xor(s, 2, 64); if (l & 2) v[0] = r; else v[2] = r;
    s = (l & 2) ? v[1] : v[3]; r = __shfl_xor(s, 2, 64); if (l & 2) v[1] = r; else v[3] = r;
}

#define GLDS16(src, dst)                                                            \
    __builtin_amdgcn_global_load_lds(                                               \
        (const __attribute__((address_space(1))) void*)(src),                       \
        (__attribute__((address_space(3))) void*)(dst), 16, 0, 0)

// ---- dtype detection, parallel: 64-block partials + tiny combine --------------
__global__ __launch_bounds__(256) void k_detect_p(const unsigned char* __restrict__ mask,
                                                  const ushort_t* __restrict__ win,
                                                  int* __restrict__ parts) {
    __shared__ int r0[256];
    __shared__ int r1[256];
    int bid = blockIdx.x, tid = threadIdx.x, mb = 0, f32 = 0;
    for (int i = bid * 256 + tid; i < 32768; i += 64 * 256)
        if ((i & 3) != 0 && mask[i] != 0) mb = 1;
    for (int i = bid * 256 + tid; i < 32768; i += 64 * 256) {
        ushort_t u = win[2 * i];
        if ((u & 0x7F80u) >= 0x4480u) f32 = 1;
    }
    r0[tid] = mb; r1[tid] = f32; __syncthreads();
    for (int st = 128; st >= 1; st >>= 1) {
        if (tid < st) { r0[tid] |= r0[tid + st]; r1[tid] |= r1[tid + st]; }
        __syncthreads();
    }
    if (tid == 0) { parts[bid] = r0[0]; parts[64 + bid] = r1[0]; }
}
__global__ void k_detect_c(const int* __restrict__ parts, int* __restrict__ flags) {
    int tid = threadIdx.x;  // 64
    int a = parts[tid], b = parts[64 + tid];
#pragma unroll
    for (int off = 32; off >= 1; off >>= 1) {
        a |= __shfl_down(a, off, 64);
        b |= __shfl_down(b, off, 64);
    }
    if (tid == 0) { flags[0] = a; flags[1] = b; }
}

// ---- fused transposes: w_ih[768x2049]->w_t[1024x768], W_cov[1024x256]->wcov_t -
template <typename IT>
__device__ __forceinline__ void tr_elem(const IT* __restrict__ in, ushort_t* __restrict__ out,
                                        int R, int C, int ld, int idx) {
    int r = idx / C, c = idx - r * C;
    out[c * R + r] = f2b(ldv(in, (size_t)r * ld + c));
}
__global__ void k_transpose2(const void* __restrict__ w_ih, ushort_t* __restrict__ w_t,
                             const void* __restrict__ W_cov, ushort_t* __restrict__ wcov_t,
                             const int* __restrict__ flags) {
    int idx = blockIdx.x * 256 + threadIdx.x;
    const int N1 = TC_ * DIM_;
    if (idx < N1) {
        if (flags[1]) tr_elem((const float*)w_ih, w_t, TC_, DIM_, KIH_, idx);
        else tr_elem((const ushort_t*)w_ih, w_t, TC_, DIM_, KIH_, idx);
    } else {
        idx -= N1;
        if (idx >= DIM_ * COV_) return;
        if (flags[1]) tr_elem((const float*)W_cov, wcov_t, DIM_, COV_, COV_, idx);
        else tr_elem((const ushort_t*)W_cov, wcov_t, DIM_, COV_, COV_, idx);
    }
}

// ---- legacy single transpose (for !fused whh_t) -------------------------------
template <typename IT>
__device__ __forceinline__ void transpose_body(const IT* __restrict__ in,
                                               ushort_t* __restrict__ out,
                                               int R, int C, int ld, int off) {
    int idx = blockIdx.x * 256 + threadIdx.x;
    if (idx >= R * C) return;
    int r = idx / C, c = idx - r * C;
    out[c * R + r] = f2b(ldv(in, (size_t)r * ld + off + c));
}
__global__ void k_transpose(const void* __restrict__ in, ushort_t* __restrict__ out,
                            int R, int C, int ld, int off, const int* __restrict__ flags) {
    if (flags[1]) transpose_body((const float*)in, out, R, C, ld, off);
    else transpose_body((const ushort_t*)in, out, R, C, ld, off);
}

// ---- bfold[j] = sum_d bcov[d]*w_ih[j,d];  also watt[j] = w_ih[j,2048] ---------
template <typename IT>
__device__ __forceinline__ void bfold_body(const IT* __restrict__ bcov,
                                           const IT* __restrict__ wih,
                                           float* __restrict__ bfold,
                                           float* __restrict__ watt) {
    int j = blockIdx.x * 4 + (threadIdx.x >> 6);
    int lane = threadIdx.x & 63;
    const IT* wr = wih + (size_t)j * KIH_;
    float a = 0.f;
    if constexpr (sizeof(IT) == 4) {
#pragma unroll
        for (int i = 0; i < 4; ++i) {
            int k = lane * 4 + 256 * i;
            float4 bv = *(const float4*)((const float*)bcov + k);
            f32x4 wv = ld4u((const float*)wr + k);
            a += bv.x * wv[0] + bv.y * wv[1] + bv.z * wv[2] + bv.w * wv[3];
        }
    } else {
#pragma unroll
        for (int i = 0; i < 16; ++i) { int k = lane + 64 * i; a += ldv(bcov, k) * ldv(wr, k); }
    }
    a = wave_reduce(a);
    if (lane == 0) { bfold[j] = a; watt[j] = ldv(wr, 2048); }
}
__global__ __launch_bounds__(256) void k_bfold(const void* __restrict__ bcov,
                                               const void* __restrict__ wih,
                                               float* __restrict__ bfold,
                                               float* __restrict__ watt,
                                               const int* __restrict__ flags) {
    if (flags[1]) bfold_body((const float*)bcov, (const float*)wih, bfold, watt);
    else bfold_body((const ushort_t*)bcov, (const ushort_t*)wih, bfold, watt);
}

// ---- wfold partials: wfp[p][c][j] = sum_{d in p*256..} W_cov[d,c]*w_ih[j,d] ---
__global__ __launch_bounds__(256) void k_wfold_p(const ushort_t* __restrict__ wcov_t,
                                                 const ushort_t* __restrict__ w_t,
                                                 float* __restrict__ wfp) {
    __shared__ float col[256];
    int c = blockIdx.x, p = blockIdx.y, tid = threadIdx.x;
    col[tid] = b2f(wcov_t[c * DIM_ + p * 256 + tid]);
    __syncthreads();
    float a0 = 0.f, a1 = 0.f, a2 = 0.f;
    const ushort_t* wt = w_t + (size_t)(p * 256) * TC_;
    for (int d = 0; d < 256; ++d) {
        float x = col[d];
        const ushort_t* wr = wt + d * TC_;
        a0 += x * b2f(wr[tid]);
        a1 += x * b2f(wr[tid + 256]);
        a2 += x * b2f(wr[tid + 512]);
    }
    float* o = wfp + ((size_t)p * COV_ + c) * TC_;
    o[tid] = a0;
    o[tid + 256] = a1;
    o[tid + 512] = a2;
}

// ---- legacy full wfold (only for the !fused fallback path) --------------------
__global__ __launch_bounds__(256) void k_wfold(const ushort_t* __restrict__ wcov_t,
                                               const ushort_t* __restrict__ w_t,
                                               float* __restrict__ wfold) {
    __shared__ float col[DIM_];
    int c = blockIdx.x, tid = threadIdx.x;
    for (int d = tid; d < DIM_; d += 256) col[d] = b2f(wcov_t[c * DIM_ + d]);
    __syncthreads();
    float a0 = 0.f, a1 = 0.f, a2 = 0.f;
    for (int d = 0; d < DIM_; ++d) {
        float x = col[d];
        const ushort_t* wr = w_t + d * TC_;
        a0 += x * b2f(wr[tid]);
        a1 += x * b2f(wr[tid + 256]);
        a2 += x * b2f(wr[tid + 512]);
    }
    wfold[c * TC_ + tid] = a0;
    wfold[c * TC_ + tid + 256] = a1;
    wfold[c * TC_ + tid + 512] = a2;
}

// ---- build Wg_t [NG=1024 rows][KG=1280 cols] bf16, GATE-INTERLEAVED -----------
template <typename IT>
__device__ __forceinline__ void buildwg_body(const IT* __restrict__ wih,
                                             const IT* __restrict__ whh,
                                             const float* __restrict__ wfp,
                                             ushort_t* __restrict__ wg) {
    int idx = blockIdx.x * 256 + threadIdx.x;
    if (idx >= NG_ * KG_) return;
    int n = idx / KG_, k = idx - n * KG_;
    int g = n & 3, cq = n >> 2;
    int j = g * COV_ + cq;  // old row index in [0,1024)
    float v;
    if (k < DIM_) {
        v = (j < TC_) ? ldv(wih, (size_t)j * KIH_ + k) : 0.f;
    } else {
        int c = k - DIM_;
        float wf = 0.f;
        if (j < TC_) {
            size_t base = (size_t)c * TC_ + j;
            wf = wfp[base] + wfp[(size_t)COV_ * TC_ + base] +
                 wfp[2 * (size_t)COV_ * TC_ + base] + wfp[3 * (size_t)COV_ * TC_ + base];
        }
        if (j < 512)      v = wf + ldv(whh, (size_t)j * COV_ + c);
        else if (j < TC_) v = wf;
        else              v = ldv(whh, (size_t)(j - 256) * COV_ + c);
    }
    wg[(size_t)n * KG_ + k] = f2b(v);
}
__global__ void k_buildwg(const void* __restrict__ wih, const void* __restrict__ whh,
                          const float* __restrict__ wfp, ushort_t* __restrict__ wg,
                          const int* __restrict__ flags) {
    if (flags[1]) buildwg_body((const float*)wih, (const float*)whh, wfp, wg);
    else buildwg_body((const ushort_t*)wih, (const ushort_t*)whh, wfp, wg);
}

// ---- target = h @ W_in^T (wave per output, float4 f32 path) -------------------
template <typename IT>
__device__ __forceinline__ void target_body(const IT* __restrict__ h,
                                            const IT* __restrict__ W_in,
                                            float* __restrict__ target) {
    int o = blockIdx.x * 4 + (threadIdx.x >> 6);
    int lane = threadIdx.x & 63;
    int b = o >> 10, d = o & (DIM_ - 1);
    const IT* hr = h + (size_t)b * DIM_;
    const IT* wr = W_in + (size_t)d * DIM_;
    float a = 0.f;
    if constexpr (sizeof(IT) == 4) {
#pragma unroll
        for (int j = 0; j < 4; ++j) {
            int k = lane * 4 + 256 * j;
            float4 x = *(const float4*)((const float*)hr + k);
            float4 w = *(const float4*)((const float*)wr + k);
            a += x.x * w.x + x.y * w.y + x.z * w.z + x.w * w.w;
        }
    } else {
#pragma unroll
        for (int j = 0; j < 16; ++j) { int k = lane + 64 * j; a += ldv(hr, k) * ldv(wr, k); }
    }
    a = wave_reduce(a);
    if (lane == 0) target[o] = a;
}
__global__ __launch_bounds__(256) void k_target_w(const void* __restrict__ h,
                                                  const void* __restrict__ W_in,
                                                  float* __restrict__ target,
                                                  const int* __restrict__ flags) {
    if (flags[1]) target_body((const float*)h, (const float*)W_in, target);
    else target_body((const ushort_t*)h, (const ushort_t*)W_in, target);
}

// ---- mvec[b,c] = sum_d target[b,d]*W_cov[d,c];  bct[b] = sum_d target*b_cov ---
template <typename IT>
__device__ __forceinline__ void mvec_body(const float* __restrict__ target,
                                          const IT* __restrict__ W_cov,
                                          const IT* __restrict__ bcov,
                                          float* __restrict__ mvec,
                                          float* __restrict__ bct) {
    __shared__ float tg[DIM_];
    __shared__ float red[256];
    int b = blockIdx.x, q = blockIdx.y, tid = threadIdx.x;
    float pb = 0.f;
    for (int k = tid; k < DIM_; k += 256) {
        float t = target[b * DIM_ + k];
        tg[k] = t; pb += t * ldv(bcov, k);
    }
    red[tid] = pb; __syncthreads();
    for (int st = 128; st >= 1; st >>= 1) {
        if (tid < st) red[tid] += red[tid + st];
        __syncthreads();
    }
    if (q == 0 && tid == 0) bct[b] = red[0];
    __syncthreads();  // red[0] read complete before red is reused below
    int cg = tid & 63, dg = tid >> 6;
    int c = q * 64 + cg;
    float acc = 0.f;
    int d0 = dg * 256;
    for (int d = d0; d < d0 + 256; ++d) acc += tg[d] * ldv(W_cov, (size_t)d * COV_ + c);
    red[dg * 64 + cg] = acc;
    __syncthreads();
    if (dg == 0)
        mvec[b * COV_ + c] = red[cg] + red[64 + cg] + red[128 + cg] + red[192 + cg];
}
__global__ __launch_bounds__(256) void k_mvec(const float* __restrict__ target,
                                              const void* __restrict__ W_cov,
                                              const void* __restrict__ bcov,
                                              float* __restrict__ mvec,
                                              float* __restrict__ bct,
                                              const int* __restrict__ flags) {
    if (flags[1]) mvec_body(target, (const float*)W_cov, (const float*)bcov, mvec, bct);
    else mvec_body(target, (const ushort_t*)W_cov, (const ushort_t*)bcov, mvec, bct);
}

// ---- raw scores + fused f32->bf16 conversion, grid (B,16) ---------------------
template <typename IT>
__device__ __forceinline__ void scoreraw_body(const IT* __restrict__ context,
                                              const IT* __restrict__ cov,
                                              const float* __restrict__ target,
                                              const float* __restrict__ mvec,
                                              const float* __restrict__ bct,
                                              float* __restrict__ scf,
                                              ushort_t* __restrict__ ctx_bf,
                                              ushort_t* __restrict__ cov_bf) {
    __shared__ float tg[DIM_];
    __shared__ float ms[COV_];
    int b = blockIdx.x, tid = threadIdx.x;
    for (int k = tid; k < DIM_; k += 256) tg[k] = target[b * DIM_ + k];
    if (tid < COV_) ms[tid] = mvec[b * COV_ + tid];
    float bc = bct[b];
    __syncthreads();
    int wave = tid >> 6, lane = tid & 63;
    int s0 = blockIdx.y * 32 + wave * 8;
    for (int i = 0; i < 8; ++i) {
        int s = s0 + i;
        size_t row = (size_t)(b * S_ + s);
        const IT* cr = context + row * DIM_;
        const IT* vr = cov + row * COV_;
        float a = 0.f;
        if constexpr (sizeof(IT) == 4) {
#pragma unroll
            for (int j = 0; j < 4; ++j) {
                int d = lane * 4 + 256 * j;
                float4 x = *(const float4*)((const float*)cr + d);
                a += x.x * tg[d] + x.y * tg[d + 1] + x.z * tg[d + 2] + x.w * tg[d + 3];
                if (ctx_bf) {
                    ushort4v u;
                    u[0] = f2b(x.x); u[1] = f2b(x.y); u[2] = f2b(x.z); u[3] = f2b(x.w);
                    *(ushort4v*)(ctx_bf + row * DIM_ + d) = u;
                }
            }
            {
                int cc = lane * 4;
                float4 x = *(const float4*)((const float*)vr + cc);
                a += x.x * ms[cc] + x.y * ms[cc + 1] + x.z * ms[cc + 2] + x.w * ms[cc + 3];
                if (cov_bf) {
                    ushort4v u;
                    u[0] = f2b(x.x); u[1] = f2b(x.y); u[2] = f2b(x.z); u[3] = f2b(x.w);
                    *(ushort4v*)(cov_bf + row * COV_ + cc) = u;
                }
            }
        } else {
#pragma unroll
            for (int j = 0; j < 16; ++j) { int d = lane + 64 * j; a += ldv(cr, d) * tg[d]; }
#pragma unroll
            for (int j = 0; j < 4; ++j) { int c = lane + 64 * j; a += ldv(vr, c) * ms[c]; }
        }
        a = wave_reduce(a);
        if (lane == 0) scf[row] = a + bc;
    }
}
__global__ __launch_bounds__(256) void k_scoreraw(const void* __restrict__ context,
                                                  const void* __restrict__ cov,
                                                  const float* __restrict__ target,
                                                  const float* __restrict__ mvec,
                                                  const float* __restrict__ bct,
                                                  float* __restrict__ scf,
                                                  ushort_t* __restrict__ ctx_bf,
                                                  ushort_t* __restrict__ cov_bf,
                                                  const int* __restrict__ flags) {
    if (flags[1]) scoreraw_body((const float*)context, (const float*)cov, target, mvec, bct,
                                scf, ctx_bf, cov_bf);
    else scoreraw_body((const ushort_t*)context, (const ushort_t*)cov, target, mvec, bct,
                       scf, ctx_bf, cov_bf);
}

// ---- wc partials + in-block softmax: grid (B,16), 32 s-rows per block ---------
// Each block recomputes the row softmax stats from scf (2KB read, bitwise
// identical across blocks); ch==0 writes attnf/out_attn.  Replaces k_softmax.
// ctx loads are short4 (8B/lane); wcp layout is thread-contiguous float4.
__global__ __launch_bounds__(256) void k_wcpart3(const ushort_t* __restrict__ ctx_bf,
                                                 const ushort_t* __restrict__ cov_bf,
                                                 const void* __restrict__ ctx_in,
                                                 const void* __restrict__ cov_in,
                                                 const float* __restrict__ scf,
                                                 const void* __restrict__ maskp,
                                                 float* __restrict__ wcp,
                                                 float* __restrict__ acp,
                                                 float* __restrict__ attnf,
                                                 float* __restrict__ attn_out,
                                                 const int* __restrict__ flags) {
    const ushort_t* C = flags[1] ? ctx_bf : (const ushort_t*)ctx_in;
    const ushort_t* V = flags[1] ? cov_bf : (const ushort_t*)cov_in;
    __shared__ float sc[512];
    __shared__ float red[256];
    __shared__ float at[32];
    int b = blockIdx.x, ch = blockIdx.y, tid = threadIdx.x;
    int mb = flags[0];
    int i0 = b * S_ + tid, i1 = i0 + 256;
    int m0 = mb ? (int)((const unsigned char*)maskp)[i0] : ((const int*)maskp)[i0];
    int m1 = mb ? (int)((const unsigned char*)maskp)[i1] : ((const int*)maskp)[i1];
    float s0 = m0 ? -INFINITY : scf[i0];
    float s1 = m1 ? -INFINITY : scf[i1];
    sc[tid] = s0; sc[tid + 256] = s1;
    red[tid] = fmaxf(s0, s1); __syncthreads();
    for (int st = 128; st >= 1; st >>= 1) {
        if (tid < st) red[tid] = fmaxf(red[tid], red[tid + st]);
        __syncthreads();
    }
    float mx = red[0]; __syncthreads();
    float e0 = expf(s0 - mx), e1 = expf(s1 - mx);
    red[tid] = e0 + e1; __syncthreads();
    for (int st = 128; st >= 1; st >>= 1) {
        if (tid < st) red[tid] += red[tid + st];
        __syncthreads();
    }
    float inv = 1.0f / red[0];
    if (ch == 0) {
        float a0 = e0 * inv, a1 = e1 * inv;
        attnf[i0] = a0; attnf[i1] = a1;
        attn_out[i0] = a0; attn_out[i1] = a1;
    }
    int s0c = ch * 32;
    if (tid < 32) at[tid] = expf(sc[s0c + tid] - mx) * inv;
    __syncthreads();
    float acv = 0.f;
    for (int s = 0; s < 32; ++s)
        acv += at[s] * b2f(V[((size_t)(b * S_ + s0c + s)) * COV_ + tid]);
    acp[((size_t)ch * B_ + b) * COV_ + tid] = acv;
    f32x4 acc = (f32x4){0.f, 0.f, 0.f, 0.f};
    for (int s = 0; s < 32; ++s) {
        float w = at[s];
        ushort4v x = *(const ushort4v*)(C + ((size_t)(b * S_ + s0c + s)) * DIM_ + 4 * tid);
        acc[0] += w * b2f(x[0]);
        acc[1] += w * b2f(x[1]);
        acc[2] += w * b2f(x[2]);
        acc[3] += w * b2f(x[3]);
    }
    *(f32x4*)(wcp + ((size_t)ch * B_ + b) * DIM_ + 4 * tid) = acc;
}

// ---- wc final: reduce 16 partials + ac@W_cov^T + b_cov (float4 layout) --------
template <typename IT>
__device__ __forceinline__ void wcfin_body(const float* __restrict__ wcp,
                                           const float* __restrict__ acp,
                                           const ushort_t* __restrict__ wcov_t,
                                           const IT* __restrict__ bcov,
                                           float* __restrict__ wc) {
    __shared__ float ac[COV_];
    int b = blockIdx.x, tid = threadIdx.x;
    float a = 0.f;
    for (int ch = 0; ch < 16; ++ch) a += acp[((size_t)ch * B_ + b) * COV_ + tid];
    ac[tid] = a;
    __syncthreads();
    f32x4 acc = (f32x4){0.f, 0.f, 0.f, 0.f};
    for (int ch = 0; ch < 16; ++ch)
        acc += *(const f32x4*)(wcp + ((size_t)ch * B_ + b) * DIM_ + 4 * tid);
    for (int c = 0; c < COV_; ++c) {
        float av = ac[c];
        ushort4v w4 = *(const ushort4v*)(wcov_t + c * DIM_ + 4 * tid);
        acc[0] += av * b2f(w4[0]);
        acc[1] += av * b2f(w4[1]);
        acc[2] += av * b2f(w4[2]);
        acc[3] += av * b2f(w4[3]);
    }
    int d = 4 * tid;
    if constexpr (sizeof(IT) == 4) {
        float4 bc4 = *(const float4*)((const float*)bcov + d);
        acc[0] += bc4.x; acc[1] += bc4.y; acc[2] += bc4.z; acc[3] += bc4.w;
    } else {
        ushort4v b4 = *(const ushort4v*)((const ushort_t*)bcov + d);
        acc[0] += b2f(b4[0]); acc[1] += b2f(b4[1]); acc[2] += b2f(b4[2]); acc[3] += b2f(b4[3]);
    }
    *(f32x4*)(wc + b * DIM_ + d) = acc;
}
__global__ __launch_bounds__(256) void k_wcfin(const float* __restrict__ wcp,
                                               const float* __restrict__ acp,
                                               const ushort_t* __restrict__ wcov_t,
                                               const void* __restrict__ bcov,
                                               float* __restrict__ wc,
                                               const int* __restrict__ flags) {
    if (flags[1]) wcfin_body(wcp, acp, wcov_t, (const float*)bcov, wc);
    else wcfin_body(wcp, acp, wcov_t, (const ushort_t*)bcov, wc);
}

// ---- h_tilde = tanh([wc, h] @ W_out^T) (wave per output, float4 f32 path) -----
template <typename IT>
__device__ __forceinline__ void htilde_body(const float* __restrict__ wc,
                                            const IT* __restrict__ h,
                                            const IT* __restrict__ W_out,
                                            float* __restrict__ out_ht) {
    int o = blockIdx.x * 4 + (threadIdx.x >> 6);
    int lane = threadIdx.x & 63;
    int b = o >> 10, d = o & (DIM_ - 1);
    const float* wcr = wc + b * DIM_;
    const IT* hr = h + (size_t)b * DIM_;
    const IT* wr = W_out + (size_t)d * 2 * DIM_;
    float a = 0.f;
    if constexpr (sizeof(IT) == 4) {
#pragma unroll
        for (int j = 0; j < 4; ++j) {
            int k = lane * 4 + 256 * j;
            float4 x = *(const float4*)(wcr + k);
            float4 w = *(const float4*)((const float*)wr + k);
            a += x.x * w.x + x.y * w.y + x.z * w.z + x.w * w.w;
        }
#pragma unroll
        for (int j = 0; j < 4; ++j) {
            int k = lane * 4 + 256 * j;
            float4 x = *(const float4*)((const float*)hr + k);
            float4 w = *(const float4*)((const float*)wr + DIM_ + k);
            a += x.x * w.x + x.y * w.y + x.z * w.z + x.w * w.w;
        }
    } else {
#pragma unroll
        for (int j = 0; j < 16; ++j) { int k = lane + 64 * j; a += wcr[k] * ldv(wr, k); }
#pragma unroll
        for (int j = 0; j < 16; ++j) { int k = lane + 64 * j; a += ldv(hr, k) * ldv(wr, DIM_ + k); }
    }
    a = wave_reduce(a);
    if (lane == 0) out_ht[o] = tanhf(a);
}
__global__ __launch_bounds__(256) void k_htilde_w(const float* __restrict__ wc,
                                                  const void* __restrict__ h,
                                                  const void* __restrict__ W_out,
                                                  float* __restrict__ out_ht,
                                                  const int* __restrict__ flags) {
    if (flags[1]) htilde_body(wc, (const float*)h, (const float*)W_out, out_ht);
    else htilde_body(wc, (const ushort_t*)h, (const ushort_t*)W_out, out_ht);
}

// ---- gxall[b,j] = b_ih[j] + bfold[j] + sum_k h[b,k]*w_ih[j,1024+k] ------------
template <typename IT>
__device__ __forceinline__ void gxh_body(const IT* __restrict__ h,
                                         const IT* __restrict__ w_ih,
                                         const IT* __restrict__ b_ih,
                                         const float* __restrict__ bfold,
                                         float* __restrict__ gxall) {
    int o = blockIdx.x * 4 + (threadIdx.x >> 6);
    int lane = threadIdx.x & 63;
    int b = o / TC_, j = o - b * TC_;
    const IT* hr = h + (size_t)b * DIM_;
    const IT* wr = w_ih + (size_t)j * KIH_ + DIM_;
    float a = 0.f;
    if constexpr (sizeof(IT) == 4) {
#pragma unroll
        for (int i = 0; i < 4; ++i) {
            int k = lane * 4 + 256 * i;
            float4 x = *(const float4*)((const float*)hr + k);
            f32x4 w = ld4u((const float*)wr + k);
            a += x.x * w[0] + x.y * w[1] + x.z * w[2] + x.w * w[3];
        }
    } else {
#pragma unroll
        for (int i = 0; i < 16; ++i) { int k = lane + 64 * i; a += ldv(hr, k) * ldv(wr, k); }
    }
    a = wave_reduce(a);
    if (lane == 0) gxall[o] = a + ldv(b_ih, j) + bfold[j];
}
__global__ __launch_bounds__(256) void k_gxh_w(const void* __restrict__ h,
                                               const void* __restrict__ w_ih,
                                               const void* __restrict__ b_ih,
                                               const float* __restrict__ bfold,
                                               float* __restrict__ gxall,
                                               const int* __restrict__ flags) {
    if (flags[1]) gxh_body((const float*)h, (const float*)w_ih, (const float*)b_ih, bfold, gxall);
    else gxh_body((const ushort_t*)h, (const ushort_t*)w_ih, (const ushort_t*)b_ih, bfold, gxall);
}

// ---- MFMA gates GEMM v6: BK=64 + unroll-2 dbuf (unchanged control) ------------
__global__ __launch_bounds__(256) void k_gemm6(const ushort_t* __restrict__ ctx_bf,
                                               const ushort_t* __restrict__ cov_bf,
                                               const void* __restrict__ ctx_in,
                                               const void* __restrict__ cov_in,
                                               const ushort_t* __restrict__ wg,
                                               const float* __restrict__ attnf,
                                               const float* __restrict__ gxall,
                                               const float* __restrict__ watt,
                                               const void* __restrict__ bhh,
                                               float* __restrict__ out_cov,
                                               const int* __restrict__ flags) {
    const int f32in = flags[1];
    const ushort_t* Xc = f32in ? ctx_bf : (const ushort_t*)ctx_in;
    const ushort_t* Xv = f32in ? cov_bf : (const ushort_t*)cov_in;
    __shared__ __align__(16) unsigned char smem[65536];
    ushort_t* A0 = (ushort_t*)smem;
    ushort_t* B0 = A0 + 8192;
    ushort_t* A1 = B0 + 8192;
    ushort_t* B1 = A1 + 8192;
    float* smN = (float*)smem;            // [128][33]
    float* smZ = smN + 128 * 33;          // [128][33]

    int tid = threadIdx.x;
    int p = blockIdx.x;
    int xcd = p & 7, t = p >> 3;
    int nb = t & 7, rb = xcd + 8 * (t >> 3);
    int n0 = nb * 128;
    int grow0 = rb * 128;
    int wave = tid >> 6, lane = tid & 63;
    int wm = wave >> 1, wn = wave & 1;
    int half = lane >> 4, r16 = lane & 15;

    const ushort_t* gAc[4]; const ushort_t* gAv[4]; const ushort_t* gB[4];
    int ldsOff[4];
#pragma unroll
    for (int j = 0; j < 4; ++j) {
        int c = wave * 256 + j * 64 + lane;
        int row = c >> 3, sl = (c & 7) ^ ((c >> 3) & 7);
        gAc[j] = Xc + (size_t)(grow0 + row) * DIM_ + sl * 8;
        gAv[j] = Xv + (size_t)(grow0 + row) * COV_ + sl * 8;
        gB[j]  = wg + (size_t)(n0 + row) * KG_ + sl * 8;
        ldsOff[j] = (wave * 256 + j * 64) * 8;
    }

    int offA[2][4], offB[2][4];
#pragma unroll
    for (int kh = 0; kh < 2; ++kh)
#pragma unroll
        for (int u = 0; u < 4; ++u) {
            int rA = wm * 64 + u * 16 + r16;
            offA[kh][u] = rA * 64 + ((kh * 4 + half) ^ (rA & 7)) * 8;
            int rB = wn * 64 + u * 16 + r16;
            offB[kh][u] = rB * 64 + ((kh * 4 + half) ^ (rB & 7)) * 8;
        }

    f32x4 acc[4][4];
#pragma unroll
    for (int i = 0; i < 4; ++i)
#pragma unroll
        for (int j = 0; j < 4; ++j) acc[i][j] = (f32x4){0.f, 0.f, 0.f, 0.f};

    auto stage = [&](int kt, ushort_t* Ad, ushort_t* Bd) {
        int k0 = kt * 64;
        if (k0 < DIM_) {
#pragma unroll
            for (int j = 0; j < 4; ++j) GLDS16(gAc[j] + k0, Ad + ldsOff[j]);
        } else {
            int kk = k0 - DIM_;
#pragma unroll
            for (int j = 0; j < 4; ++j) GLDS16(gAv[j] + kk, Ad + ldsOff[j]);
        }
#pragma unroll
        for (int j = 0; j < 4; ++j) GLDS16(gB[j] + k0, Bd + ldsOff[j]);
    };
    auto compute = [&](const ushort_t* Ac, const ushort_t* Bc) {
#pragma unroll
        for (int kh = 0; kh < 2; ++kh) {
            short8 a[4], b[4];
#pragma unroll
            for (int u = 0; u < 4; ++u) a[u] = *(const short8*)&Ac[offA[kh][u]];
#pragma unroll
            for (int u = 0; u < 4; ++u) b[u] = *(const short8*)&Bc[offB[kh][u]];
#pragma unroll
            for (int i = 0; i < 4; ++i)
#pragma unroll
                for (int j = 0; j < 4; ++j)
                    acc[i][j] = __builtin_amdgcn_mfma_f32_16x16x32_bf16(a[i], b[j], acc[i][j], 0, 0, 0);
        }
    };

    constexpr int NT = KG_ / 64;  // 20 (even)
    stage(0, A0, B0);
    __syncthreads();
#pragma unroll 1
    for (int kt = 0; kt < NT; kt += 2) {
        stage(kt + 1, A1, B1);
        compute(A0, B0);
        __syncthreads();
        if (kt + 2 < NT) stage(kt + 2, A0, B0);
        compute(A1, B1);
        __syncthreads();
    }

    // ---- fused GRU epilogue ----
    int l = lane;
    int bb = grow0 >> 9;
    const float* gx = gxall + bb * TC_;
    int rloc[4]; float atv[4];
#pragma unroll
    for (int i = 0; i < 4; ++i) {
        rloc[i] = wm * 64 + 16 * i + ((l >> 4) << 2) + (l & 3);
        atv[i] = attnf[grow0 + rloc[i]];
    }
#pragma unroll
    for (int j = 0; j < 4; ++j) {
        int cl = wn * 16 + 4 * j + ((l >> 2) & 3);
        int c = (n0 >> 2) + cl;
        float gxR = gx[c], gxZ = gx[COV_ + c], gxN = gx[2 * COV_ + c];
        float waR = watt[c], waZ = watt[COV_ + c], waN = watt[2 * COV_ + c];
        float bhR, bhZ, bhN;
        if (f32in) {
            const float* bp = (const float*)bhh;
            bhR = bp[c]; bhZ = bp[COV_ + c]; bhN = bp[2 * COV_ + c];
        } else {
            const ushort_t* bp = (const ushort_t*)bhh;
            bhR = b2f(bp[c]); bhZ = b2f(bp[COV_ + c]); bhN = b2f(bp[2 * COV_ + c]);
        }
#pragma unroll
        for (int i = 0; i < 4; ++i) {
            f32x4 v = acc[i][j];
            xpose4(v, l);
            float at = atv[i];
            float aR  = v[0] + gxR + at * waR + bhR;
            float aZ  = v[1] + gxZ + at * waZ + bhZ;
            float aXN = v[2] + gxN + at * waN;
            float aHN = v[3] + bhN;
            float r = 1.f / (1.f + expf(-aR));
            float z = 1.f / (1.f + expf(-aZ));
            float nn = tanhf(aXN + r * aHN);
            smN[rloc[i] * 33 + cl] = nn;
            smZ[rloc[i] * 33 + cl] = z;
        }
    }
    __syncthreads();
    int cbase = nb * 32;
    for (int u = tid; u < 128 * 8; u += 256) {
        int rl = u >> 3, c4 = (u & 7) * 4;
        float n0v = smN[rl * 33 + c4 + 0], n1v = smN[rl * 33 + c4 + 1];
        float n2v = smN[rl * 33 + c4 + 2], n3v = smN[rl * 33 + c4 + 3];
        float z0 = smZ[rl * 33 + c4 + 0], z1 = smZ[rl * 33 + c4 + 1];
        float z2 = smZ[rl * 33 + c4 + 2], z3 = smZ[rl * 33 + c4 + 3];
        size_t base = (size_t)(grow0 + rl) * COV_ + cbase + c4;
        float h0v, h1v, h2v, h3v;
        if (f32in) {
            float4 hv = *(const float4*)((const float*)cov_in + base);
            h0v = hv.x; h1v = hv.y; h2v = hv.z; h3v = hv.w;
        } else {
            ushort4v hv = *(const ushort4v*)((const ushort_t*)cov_in + base);
            h0v = b2f(hv[0]); h1v = b2f(hv[1]); h2v = b2f(hv[2]); h3v = b2f(hv[3]);
        }
        float4 o;
        o.x = (1.f - z0) * n0v + z0 * h0v;
        o.y = (1.f - z1) * n1v + z1 * h1v;
        o.z = (1.f - z2) * n2v + z2 * h2v;
        o.w = (1.f - z3) * n3v + z3 * h3v;
        *(float4*)(out_cov + base) = o;
    }
}

// ---- legacy GRU (fallback when ws too small) ----------------------------------
template <typename IT>
__device__ __forceinline__ void gru_body(const IT* __restrict__ context,
                                         const IT* __restrict__ cov,
                                         const float* __restrict__ attnf,
                                         const float* __restrict__ gxall,
                                         const float* __restrict__ watt,
                                         const ushort_t* __restrict__ w_t,
                                         const float* __restrict__ wfold,
                                         const ushort_t* __restrict__ whh_t,
                                         const IT* __restrict__ bhh,
                                         float* __restrict__ out_cov) {
    __shared__ float xc[8][DIM_];
    __shared__ float h0s[8][COV_];
    __shared__ float atn[8];
    int base = blockIdx.x * 8, tid = threadIdx.x;
    int b = base / S_;
    for (int i = tid; i < 8 * DIM_; i += 256)
        ((float*)xc)[i] = ldv(context, (size_t)base * DIM_ + i);
    for (int i = tid; i < 8 * COV_; i += 256)
        ((float*)h0s)[i] = ldv(cov, (size_t)base * COV_ + i);
    if (tid < 8) atn[tid] = attnf[base + tid];
    __syncthreads();
    int c = tid;
    float gxR = gxall[b * TC_ + c], gxZ = gxall[b * TC_ + 256 + c], gxN = gxall[b * TC_ + 512 + c];
    float bhR = ldv(bhh, c), bhZ = ldv(bhh, 256 + c), bhN = ldv(bhh, 512 + c);
    float waR = watt[c], waZ = watt[256 + c], waN = watt[512 + c];
    float aR[8], aZ[8], aXN[8], aHN[8];
#pragma unroll
    for (int g = 0; g < 8; ++g) {
        float a = atn[g];
        aR[g] = gxR + bhR + a * waR;
        aZ[g] = gxZ + bhZ + a * waZ;
        aXN[g] = gxN + a * waN;
        aHN[g] = bhN;
    }
    for (int k = 0; k < DIM_; ++k) {
        const ushort_t* row = w_t + k * TC_;
        float wr = b2f(row[c]), wz = b2f(row[256 + c]), wn = b2f(row[512 + c]);
#pragma unroll
        for (int g = 0; g < 8; ++g) {
            float x = xc[g][k];
            aR[g] += x * wr; aZ[g] += x * wz; aXN[g] += x * wn;
        }
    }
    for (int k = 0; k < COV_; ++k) {
        const float* row = wfold + k * TC_;
        float wr = row[c], wz = row[256 + c], wn = row[512 + c];
#pragma unroll
        for (int g = 0; g < 8; ++g) {
            float x = h0s[g][k];
            aR[g] += x * wr; aZ[g] += x * wz; aXN[g] += x * wn;
        }
    }
    for (int k = 0; k < COV_; ++k) {
        const ushort_t* row = whh_t + k * TC_;
        float wr = b2f(row[c]), wz = b2f(row[256 + c]), wn = b2f(row[512 + c]);
#pragma unroll
        for (int g = 0; g < 8; ++g) {
            float hh = h0s[g][k];
            aR[g] += hh * wr; aZ[g] += hh * wz; aHN[g] += hh * wn;
        }
    }
#pragma unroll
    for (int g = 0; g < 8; ++g) {
        float r = 1.f / (1.f + expf(-aR[g]));
        float z = 1.f / (1.f + expf(-aZ[g]));
        float n = tanhf(aXN[g] + r * aHN[g]);
        float h0c = h0s[g][c];
        out_cov[(size_t)(base + g) * COV_ + c] = (1.f - z) * n + z * h0c;
    }
}
__global__ __launch_bounds__(256) void k_gru_f(const void* __restrict__ context,
                                               const void* __restrict__ cov,
                                               const float* __restrict__ attnf,
                                               const float* __restrict__ gxall,
                                               const float* __restrict__ watt,
                                               const ushort_t* __restrict__ w_t,
                                               const float* __restrict__ wfold,
                                               const ushort_t* __restrict__ whh_t,
                                               const void* __restrict__ bhh,
                                               float* __restrict__ out_cov,
                                               const int* __restrict__ flags) {
    if (flags[1]) gru_body((const float*)context, (const float*)cov, attnf, gxall, watt,
                           w_t, wfold, whh_t, (const float*)bhh, out_cov);
    else gru_body((const ushort_t*)context, (const ushort_t*)cov, attnf, gxall, watt,
                  w_t, wfold, whh_t, (const ushort_t*)bhh, out_cov);
}

extern "C" void kernel_launch(void* const* d_in, const int* in_sizes, int n_in,
                              void* d_out, int out_size, void* d_ws, size_t ws_size,
                              hipStream_t stream) {
    const void* h       = d_in[0];
    const void* context = d_in[1];
    const void* cov     = d_in[2];
    const void* W_in    = d_in[3];
    const void* W_out   = d_in[4];
    const void* W_cov   = d_in[5];
    const void* b_cov   = d_in[6];
    const void* w_ih    = d_in[7];
    const void* w_hh    = d_in[8];
    const void* b_ih    = d_in[9];
    const void* b_hh    = d_in[10];
    const void* maskp   = d_in[11];

    float* out = (float*)d_out;
    float* out_ht   = out;
    float* out_attn = out + B_ * DIM_;
    float* out_cov  = out + B_ * DIM_ + B_ * S_;

    char* ws = (char*)d_ws;
    size_t o = 0;
    float* target = (float*)(ws + o); o += (size_t)B_ * DIM_ * 4;
    float* attnf  = (float*)(ws + o); o += (size_t)B_ * S_ * 4;
    float* wc     = (float*)(ws + o); o += (size_t)B_ * DIM_ * 4;
    float* gxall  = (float*)(ws + o); o += (size_t)B_ * TC_ * 4;
    float* watt   = (float*)(ws + o); o += 4096;
    float* mvec   = (float*)(ws + o); o += (size_t)B_ * COV_ * 4;
    float* bct    = (float*)(ws + o); o += 4096;
    float* bfold  = (float*)(ws + o); o += 4096;
    float* wfold  = (float*)(ws + o); o += (size_t)COV_ * TC_ * 4;
    float* wfp    = (float*)(ws + o); o += (size_t)4 * COV_ * TC_ * 4;  // 3 MB partials
    int* dparts   = (int*)(ws + o);   o += 512;
    ushort_t* w_t    = (ushort_t*)(ws + o); o += (size_t)DIM_ * TC_ * 2;
    ushort_t* whh_t  = (ushort_t*)(ws + o); o += (size_t)COV_ * TC_ * 2;
    ushort_t* wcov_t = (ushort_t*)(ws + o); o += (size_t)COV_ * DIM_ * 2;
    int* flags = (int*)(ws + o); o += 256;
    float* scf   = (float*)(ws + o); o += (size_t)B_ * S_ * 4;
    float* wcp   = (float*)(ws + o); o += (size_t)16 * B_ * DIM_ * 4;  // 4 MB
    float* acp   = (float*)(ws + o); o += (size_t)16 * B_ * COV_ * 4;  // 1 MB
    ushort_t* wg = (ushort_t*)(ws + o); o += (size_t)NG_ * KG_ * 2;
    ushort_t* ctx_bf = (ushort_t*)(ws + o); o += (size_t)B_ * S_ * DIM_ * 2;  // 67 MB
    ushort_t* cov_bf = (ushort_t*)(ws + o); o += (size_t)B_ * S_ * COV_ * 2;  // 17 MB
    size_t fixed = o;

    const size_t TOTAL_ROWS = (size_t)B_ * S_;  // 32768
    const bool fused = ws_size >= fixed;

    // dtype detection (parallel) + weight prep
    k_detect_p<<<64, 256, 0, stream>>>((const unsigned char*)maskp, (const ushort_t*)W_in, dparts);
    k_detect_c<<<1, 64, 0, stream>>>(dparts, flags);
    k_transpose2<<<(TC_ * DIM_ + DIM_ * COV_) / 256, 256, 0, stream>>>(w_ih, w_t, W_cov,
                                                                       wcov_t, flags);
    if (!fused)
        k_transpose<<<(TC_ * COV_) / 256, 256, 0, stream>>>(w_hh, whh_t, TC_, COV_, COV_, 0, flags);
    k_bfold<<<TC_ / 4, 256, 0, stream>>>(b_cov, w_ih, bfold, watt, flags);
    if (fused) {
        k_wfold_p<<<dim3(COV_, 4), 256, 0, stream>>>(wcov_t, w_t, wfp);
        k_buildwg<<<(NG_ * KG_ + 255) / 256, 256, 0, stream>>>(w_ih, w_hh, wfp, wg, flags);
    } else {
        k_wfold<<<COV_, 256, 0, stream>>>(wcov_t, w_t, wfold);
    }

    // attention path (scoreraw also emits the bf16 copies of ctx/cov)
    k_target_w<<<(B_ * DIM_) / 4, 256, 0, stream>>>(h, W_in, target, flags);
    k_mvec<<<dim3(B_, 4), 256, 0, stream>>>(target, W_cov, b_cov, mvec, bct, flags);
    k_scoreraw<<<dim3(B_, 16), 256, 0, stream>>>(context, cov, target, mvec, bct, scf,
                                                 fused ? ctx_bf : nullptr,
                                                 fused ? cov_bf : nullptr, flags);
    // wcpart3 includes the masked softmax (writes attnf + out_attn from ch==0)
    if (fused)
        k_wcpart3<<<dim3(B_, 16), 256, 0, stream>>>(ctx_bf, cov_bf, context, cov, scf, maskp,
                                                    wcp, acp, attnf, out_attn, flags);
    else
        k_wcpart3<<<dim3(B_, 16), 256, 0, stream>>>((const ushort_t*)context, (const ushort_t*)cov,
                                                    context, cov, scf, maskp,
                                                    wcp, acp, attnf, out_attn, flags);
    k_wcfin<<<B_, 256, 0, stream>>>(wcp, acp, wcov_t, b_cov, wc, flags);
    k_htilde_w<<<(B_ * DIM_) / 4, 256, 0, stream>>>(wc, h, W_out, out_ht, flags);

    // GRU coverage path (single fused GEMM+activation)
    k_gxh_w<<<(B_ * TC_) / 4, 256, 0, stream>>>(h, w_ih, b_ih, bfold, gxall, flags);
    if (fused) {
        int nblk = (int)(TOTAL_ROWS / 128) * (NG_ / 128);  // 2048
        k_gemm6<<<nblk, 256, 0, stream>>>(ctx_bf, cov_bf, context, cov, wg, attnf,
                                          gxall, watt, b_hh, out_cov, flags);
    } else {
        k_gru_f<<<(B_ * S_) / 8, 256, 0, stream>>>(context, cov, attnf, gxall, watt,
                                                   w_t, wfold, whh_t, b_hh, out_cov, flags);
    }
}